// Round 2
// baseline (947.835 us; speedup 1.0000x reference)
//
#include <hip/hip_runtime.h>

typedef unsigned int u32;

// ---------- CSR build ----------
__global__ __launch_bounds__(256) void count_deg(const int* __restrict__ eidx,
                                                 int* __restrict__ degi, int E) {
  int e = blockIdx.x * 256 + threadIdx.x;
  if (e >= E) return;
  // undirected: directed edge e lands at dst0[e] (forward) and src0[e] (reversed)
  atomicAdd(&degi[eidx[E + e]], 1);
  atomicAdd(&degi[eidx[e]], 1);
}

__global__ __launch_bounds__(1024) void csr_scan(const int* __restrict__ degi,
                                                 int* __restrict__ rowptr,
                                                 float* __restrict__ dis, int n) {
  __shared__ int sums[1024];
  int tid = threadIdx.x;
  const int CH = (n + 1023) / 1024;
  int base = tid * CH;
  int s = 0;
  for (int i = 0; i < CH; ++i) { int j = base + i; if (j < n) s += degi[j]; }
  sums[tid] = s;
  __syncthreads();
  for (int off = 1; off < 1024; off <<= 1) {
    int v = sums[tid];
    int add = (tid >= off) ? sums[tid - off] : 0;
    __syncthreads();
    sums[tid] = v + add;
    __syncthreads();
  }
  int run = sums[tid] - s;  // exclusive prefix of this thread's chunk
  for (int i = 0; i < CH; ++i) {
    int j = base + i;
    if (j < n) { rowptr[j] = run; run += degi[j]; }
  }
  if (tid == 1023) rowptr[n] = sums[1023];
  for (int j = tid; j < n; j += 1024) {
    int d = degi[j];
    dis[j] = d > 0 ? rsqrtf((float)d) : 0.0f;
  }
}

__global__ __launch_bounds__(256) void fill_csr(const int* __restrict__ eidx,
                                                const int* __restrict__ rowptr,
                                                int* __restrict__ cursor,
                                                int* __restrict__ col,
                                                int* __restrict__ erow, int E) {
  int i = blockIdx.x * 256 + threadIdx.x;
  int E2 = 2 * E;
  if (i >= E2) return;
  int e = (i < E) ? i : i - E;
  int s, d;
  if (i < E) { s = eidx[e]; d = eidx[E + e]; }
  else       { s = eidx[E + e]; d = eidx[e]; }
  int pos = rowptr[d] + atomicAdd(&cursor[d], 1);
  col[pos] = s;
  erow[pos] = e;
}

// ---------- node-level GEMM: C[M,KO] = A[M,KI] @ W[KI,KO] + extras (all fp32) ----------
template<int KI, int KO>
__global__ __launch_bounds__(128) void gemm_node(
    const float* __restrict__ A, const float* __restrict__ W, float* __restrict__ Cout,
    const float* __restrict__ Cin, const float* __restrict__ bias,
    const int* __restrict__ degi, const float* __restrict__ resid, int M, int relu) {
  const int ROWS = 8;
  int t = threadIdx.x;
  int base = blockIdx.x * ROWS;
  __shared__ float Al[ROWS * KI];
  for (int i = t; i < ROWS * KI; i += 128) {
    int r = i / KI, k = i - r * KI;
    int row = base + r;
    Al[i] = (row < M) ? A[(size_t)row * KI + k] : 0.f;
  }
  __syncthreads();
  if (KO == 128) {
    float acc[ROWS];
#pragma unroll
    for (int r = 0; r < ROWS; ++r) acc[r] = 0.f;
    for (int k = 0; k < KI; ++k) {
      float w = W[k * 128 + t];
#pragma unroll
      for (int r = 0; r < ROWS; ++r) acc[r] += Al[r * KI + k] * w;
    }
#pragma unroll
    for (int r = 0; r < ROWS; ++r) {
      int row = base + r;
      if (row >= M) break;
      float v = acc[r];
      if (Cin)   v += Cin[(size_t)row * 128 + t];
      if (bias)  { float b = bias[t]; v += degi ? b * (float)degi[row] : b; }
      if (resid) v += resid[(size_t)row * 128 + t];
      if (relu)  v = fmaxf(v, 0.f);
      Cout[(size_t)row * 128 + t] = v;
    }
  } else {  // KO == 16: 8 rows x 16 out-units = 128 threads
    int r = t >> 4, u = t & 15;
    int row = base + r;
    float acc = 0.f;
    for (int k = 0; k < KI; ++k) acc += Al[r * KI + k] * W[k * 16 + u];
    if (row < M) {
      float v = acc;
      if (Cin)   v += Cin[(size_t)row * 16 + u];
      if (bias)  { float b = bias[u]; v += degi ? b * (float)degi[row] : b; }
      if (resid) v += resid[(size_t)row * 16 + u];
      if (relu)  v = fmaxf(v, 0.f);
      Cout[(size_t)row * 16 + u] = v;
    }
  }
}

// ---------- EA hidden-sum gather: Hsum[n] = sum_e relu(pb[n] + q[src] + ea@W1ea) ----------
__global__ __launch_bounds__(128) void ea_gather(
    const float* __restrict__ pb, const float* __restrict__ q,
    const float* __restrict__ w1ea /*[16,128]*/, const float* __restrict__ ea /*[E,16]*/,
    const int* __restrict__ rowptr, const int* __restrict__ col,
    const int* __restrict__ erow, float* __restrict__ Hsum) {
  int node = blockIdx.x;
  int t = threadIdx.x;
  __shared__ float wl[16 * 128];
  for (int i = t; i < 16 * 128; i += 128) wl[i] = w1ea[i];
  __syncthreads();
  float pbv = pb[(size_t)node * 128 + t];
  float acc = 0.f;
  int e1 = rowptr[node + 1];
  for (int e = rowptr[node]; e < e1; ++e) {
    int s = col[e];
    int r = erow[e];
    float qv = q[(size_t)s * 128 + t];
    const float4* p = reinterpret_cast<const float4*>(ea + (size_t)r * 16);
    float4 a0 = p[0], a1 = p[1], a2 = p[2], a3 = p[3];
    float v[16] = {a0.x, a0.y, a0.z, a0.w, a1.x, a1.y, a1.z, a1.w,
                   a2.x, a2.y, a2.z, a2.w, a3.x, a3.y, a3.z, a3.w};
    float proj = 0.f;
#pragma unroll
    for (int k = 0; k < 16; ++k) proj += v[k] * wl[k * 128 + t];
    acc += fmaxf(pbv + qv + proj, 0.f);
  }
  Hsum[(size_t)node * 128 + t] = acc;
}

// ---------- TAG hop gather: out[n] = dis[n] * sum_e dis[src]*hk[src] ----------
__global__ __launch_bounds__(128) void tag_gather(
    const float* __restrict__ hk, const float* __restrict__ dis,
    const int* __restrict__ rowptr, const int* __restrict__ col,
    float* __restrict__ out) {
  int node = blockIdx.x;
  int t = threadIdx.x;
  float acc = 0.f;
  int e1 = rowptr[node + 1];
  for (int e = rowptr[node]; e < e1; ++e) {
    int s = col[e];
    acc += dis[s] * hk[(size_t)s * 128 + t];
  }
  out[(size_t)node * 128 + t] = dis[node] * acc;
}

extern "C" void kernel_launch(void* const* d_in, const int* in_sizes, int n_in,
                              void* d_out, int out_size, void* d_ws, size_t ws_size,
                              hipStream_t stream) {
  const float* x      = (const float*)d_in[0];
  const float* mask   = (const float*)d_in[1];
  const float* ea     = (const float*)d_in[2];
  const int*   eidx   = (const int*)d_in[3];
  const float* m_w1   = (const float*)d_in[4];
  const float* m_b1   = (const float*)d_in[5];
  const float* m_w2   = (const float*)d_in[6];
  const float* m_b2   = (const float*)d_in[7];
  const float* ea0_w1 = (const float*)d_in[8];
  const float* ea0_b1 = (const float*)d_in[9];
  const float* ea0_w2 = (const float*)d_in[10];
  const float* ea0_b2 = (const float*)d_in[11];
  const float* tag0_w = (const float*)d_in[12];
  const float* tag0_b = (const float*)d_in[13];
  const float* ea1_w1 = (const float*)d_in[14];
  const float* ea1_b1 = (const float*)d_in[15];
  const float* ea1_w2 = (const float*)d_in[16];
  const float* ea1_b2 = (const float*)d_in[17];
  const float* tag1_w = (const float*)d_in[18];
  const float* tag1_b = (const float*)d_in[19];
  const float* ea2_w1 = (const float*)d_in[20];
  const float* ea2_b1 = (const float*)d_in[21];
  const float* ea2_w2 = (const float*)d_in[22];
  const float* ea2_b2 = (const float*)d_in[23];

  const int N = in_sizes[0] / 16;   // 20000
  const int E = in_sizes[2] / 16;   // 160000
  const int E2 = 2 * E;

  // ---- workspace carve (256B-aligned); total ~35 MB ----
  char* w = (char*)d_ws;
  auto alloc = [&](size_t bytes) { char* p = w; w += (bytes + 255) & ~(size_t)255; return p; };
  int*   degi   = (int*)alloc((size_t)N * 4);
  int*   cursor = (int*)alloc((size_t)N * 4);
  int*   rowptr = (int*)alloc((size_t)(N + 1) * 4);
  float* dis    = (float*)alloc((size_t)N * 4);
  int*   col    = (int*)alloc((size_t)E2 * 4);
  int*   erow   = (int*)alloc((size_t)E2 * 4);
  float* h16    = (float*)alloc((size_t)N * 16 * 4);
  float* B0     = (float*)alloc((size_t)N * 128 * 4);
  float* B1     = (float*)alloc((size_t)N * 128 * 4);
  float* B2     = (float*)alloc((size_t)N * 128 * 4);
  (void)ws_size; (void)n_in; (void)out_size;

  // ---- CSR build ----
  hipMemsetAsync(degi, 0, (size_t)N * 4, stream);
  hipMemsetAsync(cursor, 0, (size_t)N * 4, stream);
  count_deg<<<(E + 255) / 256, 256, 0, stream>>>(eidx, degi, E);
  csr_scan<<<1, 1024, 0, stream>>>(degi, rowptr, dis, N);
  fill_csr<<<(E2 + 255) / 256, 256, 0, stream>>>(eidx, rowptr, cursor, col, erow, E);

  const int gb = (N + 7) / 8;

  // ---- mask MLP + residual: h16 = relu(mask@m_w1+b1)@m_w2 + b2 + x ----
  gemm_node<16, 128><<<gb, 128, 0, stream>>>(mask, m_w1, B0, nullptr, m_b1, nullptr, nullptr, N, 1);
  gemm_node<128, 16><<<gb, 128, 0, stream>>>(B0, m_w2, h16, nullptr, m_b2, nullptr, x, N, 0);

  // ---- EA0 (node feat 16): h1 = relu((sum_e relu(z_e)) @ w2 + deg*b2) -> B0 ----
  gemm_node<16, 128><<<gb, 128, 0, stream>>>(h16, ea0_w1, B0, nullptr, ea0_b1, nullptr, nullptr, N, 0);            // pb = h@W_dst + b1
  gemm_node<16, 128><<<gb, 128, 0, stream>>>(h16, ea0_w1 + 16 * 128, B1, nullptr, nullptr, nullptr, nullptr, N, 0); // q = h@W_src
  ea_gather<<<N, 128, 0, stream>>>(B0, B1, ea0_w1 + 32 * 128, ea, rowptr, col, erow, B2);
  gemm_node<128, 128><<<gb, 128, 0, stream>>>(B2, ea0_w2, B0, nullptr, ea0_b2, degi, nullptr, N, 1);  // h1 -> B0

  // ---- TAG0: h2 = relu(sum_k (L^k h1)@lin_k + bias) -> B0 ----
  gemm_node<128, 128><<<gb, 128, 0, stream>>>(B0, tag0_w, B1, nullptr, nullptr, nullptr, nullptr, N, 0);            // acc = h@lin0 -> B1
  tag_gather<<<N, 128, 0, stream>>>(B0, dis, rowptr, col, B2);                                                      // B2 = L h
  gemm_node<128, 128><<<gb, 128, 0, stream>>>(B2, tag0_w + 16384, B1, B1, nullptr, nullptr, nullptr, N, 0);
  tag_gather<<<N, 128, 0, stream>>>(B2, dis, rowptr, col, B0);                                                      // B0 = L^2 h
  gemm_node<128, 128><<<gb, 128, 0, stream>>>(B0, tag0_w + 2 * 16384, B1, B1, nullptr, nullptr, nullptr, N, 0);
  tag_gather<<<N, 128, 0, stream>>>(B0, dis, rowptr, col, B2);                                                      // B2 = L^3 h
  gemm_node<128, 128><<<gb, 128, 0, stream>>>(B2, tag0_w + 3 * 16384, B0, B1, tag0_b, nullptr, nullptr, N, 1);      // h2 -> B0

  // ---- EA1 (node feat 128): h3 -> B1 ----
  gemm_node<128, 128><<<gb, 128, 0, stream>>>(B0, ea1_w1, B1, nullptr, ea1_b1, nullptr, nullptr, N, 0);              // pb
  gemm_node<128, 128><<<gb, 128, 0, stream>>>(B0, ea1_w1 + 128 * 128, B2, nullptr, nullptr, nullptr, nullptr, N, 0); // q
  ea_gather<<<N, 128, 0, stream>>>(B1, B2, ea1_w1 + 256 * 128, ea, rowptr, col, erow, B0);
  gemm_node<128, 128><<<gb, 128, 0, stream>>>(B0, ea1_w2, B1, nullptr, ea1_b2, degi, nullptr, N, 1);  // h3 -> B1

  // ---- TAG1: h4 -> B1 ----
  gemm_node<128, 128><<<gb, 128, 0, stream>>>(B1, tag1_w, B0, nullptr, nullptr, nullptr, nullptr, N, 0);            // acc -> B0
  tag_gather<<<N, 128, 0, stream>>>(B1, dis, rowptr, col, B2);                                                      // B2 = L h
  gemm_node<128, 128><<<gb, 128, 0, stream>>>(B2, tag1_w + 16384, B0, B0, nullptr, nullptr, nullptr, N, 0);
  tag_gather<<<N, 128, 0, stream>>>(B2, dis, rowptr, col, B1);                                                      // B1 = L^2 h
  gemm_node<128, 128><<<gb, 128, 0, stream>>>(B1, tag1_w + 2 * 16384, B0, B0, nullptr, nullptr, nullptr, N, 0);
  tag_gather<<<N, 128, 0, stream>>>(B1, dis, rowptr, col, B2);                                                      // B2 = L^3 h
  gemm_node<128, 128><<<gb, 128, 0, stream>>>(B2, tag1_w + 3 * 16384, B1, B0, tag1_b, nullptr, nullptr, N, 1);      // h4 -> B1

  // ---- EA2 (final, no relu, out 16, fp32) ----
  gemm_node<128, 128><<<gb, 128, 0, stream>>>(B1, ea2_w1, B0, nullptr, ea2_b1, nullptr, nullptr, N, 0);              // pb
  gemm_node<128, 128><<<gb, 128, 0, stream>>>(B1, ea2_w1 + 128 * 128, B2, nullptr, nullptr, nullptr, nullptr, N, 0); // q
  ea_gather<<<N, 128, 0, stream>>>(B0, B2, ea2_w1 + 256 * 128, ea, rowptr, col, erow, B1);
  gemm_node<128, 16><<<gb, 128, 0, stream>>>(B1, ea2_w2, (float*)d_out, nullptr, ea2_b2, degi, nullptr, N, 0);
}

// Round 3
// 782.757 us; speedup vs baseline: 1.2109x; 1.2109x over previous
//
#include <hip/hip_runtime.h>

typedef unsigned short u16;
typedef unsigned int u32;

using bfrag = __attribute__((ext_vector_type(8))) short;   // 8 bf16 (4 VGPRs)
using f32x4 = __attribute__((ext_vector_type(4))) float;   // 4 fp32 acc

// ---------- bf16 helpers ----------
__device__ __forceinline__ float b2f(u16 u) {
  union { u32 i; float f; } c; c.i = ((u32)u) << 16; return c.f;
}
__device__ __forceinline__ u16 f2b(float f) {  // round-to-nearest-even
  union { float f; u32 i; } c; c.f = f;
  u32 x = c.i;
  u32 r = x + 0x7fffu + ((x >> 16) & 1u);
  return (u16)(r >> 16);
}

// ---------- CSR build ----------
__global__ __launch_bounds__(256) void count_deg(const int* __restrict__ eidx,
                                                 int* __restrict__ degi, int E) {
  int e = blockIdx.x * 256 + threadIdx.x;
  if (e >= E) return;
  atomicAdd(&degi[eidx[E + e]], 1);
  atomicAdd(&degi[eidx[e]], 1);
}

__global__ __launch_bounds__(1024) void csr_scan(const int* __restrict__ degi,
                                                 int* __restrict__ rowptr,
                                                 float* __restrict__ dis, int n) {
  __shared__ int sums[1024];
  int tid = threadIdx.x;
  const int CH = (n + 1023) / 1024;
  int base = tid * CH;
  int s = 0;
  for (int i = 0; i < CH; ++i) { int j = base + i; if (j < n) s += degi[j]; }
  sums[tid] = s;
  __syncthreads();
  for (int off = 1; off < 1024; off <<= 1) {
    int v = sums[tid];
    int add = (tid >= off) ? sums[tid - off] : 0;
    __syncthreads();
    sums[tid] = v + add;
    __syncthreads();
  }
  int run = sums[tid] - s;
  for (int i = 0; i < CH; ++i) {
    int j = base + i;
    if (j < n) { rowptr[j] = run; run += degi[j]; }
  }
  if (tid == 1023) rowptr[n] = sums[1023];
  for (int j = tid; j < n; j += 1024) {
    int d = degi[j];
    dis[j] = d > 0 ? rsqrtf((float)d) : 0.0f;
  }
}

__global__ __launch_bounds__(256) void fill_csr(const int* __restrict__ eidx,
                                                const int* __restrict__ rowptr,
                                                int* __restrict__ cursor,
                                                int* __restrict__ col,
                                                int* __restrict__ erow, int E) {
  int i = blockIdx.x * 256 + threadIdx.x;
  int E2 = 2 * E;
  if (i >= E2) return;
  int e = (i < E) ? i : i - E;
  int s, d;
  if (i < E) { s = eidx[e]; d = eidx[E + e]; }
  else       { s = eidx[E + e]; d = eidx[e]; }
  int pos = rowptr[d] + atomicAdd(&cursor[d], 1);
  col[pos] = s;
  erow[pos] = e;
}

// ---------- weight prep: fp32 [128k][128n] -> bf16 [128n][128k] in workspace ----------
__global__ __launch_bounds__(256) void prep_wt(
    const float* __restrict__ ea0_w2, const float* __restrict__ tag0_w,
    const float* __restrict__ ea1_w1, const float* __restrict__ ea1_w2,
    const float* __restrict__ tag1_w, const float* __restrict__ ea2_w1,
    u16* __restrict__ Wt) {
  int mat = blockIdx.x >> 3, chunk = blockIdx.x & 7;
  const float* src;
  if      (mat == 0)  src = ea0_w2;
  else if (mat <= 4)  src = tag0_w + (mat - 1) * 16384;
  else if (mat == 5)  src = ea1_w1;
  else if (mat == 6)  src = ea1_w1 + 16384;
  else if (mat == 7)  src = ea1_w2;
  else if (mat <= 11) src = tag1_w + (mat - 8) * 16384;
  else if (mat == 12) src = ea2_w1;
  else                src = ea2_w1 + 16384;
  u16* dst = Wt + mat * 16384;
  int t = threadIdx.x;
  for (int i = 0; i < 8; ++i) {
    int idx = chunk * 2048 + i * 256 + t;
    int k = idx >> 7, n = idx & 127;
    dst[n * 128 + k] = f2b(src[idx]);
  }
}

// ---------- MFMA GEMM: C[M,128] = A[M,128]bf16 @ W[128,128] (+Cin +bias/deg*bias +relu) ----------
// Wt is bf16 [n][k] (pre-transposed). 256 threads = 4 waves; 64 rows/block.
template<bool OUTBF16>
__global__ __launch_bounds__(256) void gemm_mfma(
    const u16* __restrict__ A, const u16* __restrict__ Wt,
    void* __restrict__ Cout, const float* __restrict__ Cin,
    const float* __restrict__ bias, const int* __restrict__ degi,
    int M, int relu) {
  __shared__ u16 Alds[64 * 136];   // row stride 136 bf16 (272 B, 16B-aligned, 2-way banks = free)
  __shared__ u16 Wlds[128 * 136];
  int t = threadIdx.x;
  int base = blockIdx.x * 64;
  // stage Wt (16384 bf16): coalesced 16B per thread
#pragma unroll
  for (int i = 0; i < 8; ++i) {
    int idx = (i * 256 + t) * 8;
    int n = idx >> 7, k = idx & 127;
    uint4 v = *(const uint4*)(Wt + idx);
    *(uint4*)(Wlds + n * 136 + k) = v;
  }
  // stage A (64x128 bf16)
#pragma unroll
  for (int i = 0; i < 4; ++i) {
    int idx = (i * 256 + t) * 8;
    int r = idx >> 7, k = idx & 127;
    int row = base + r;
    uint4 v = make_uint4(0, 0, 0, 0);
    if (row < M) v = *(const uint4*)(A + (size_t)row * 128 + k);
    *(uint4*)(Alds + r * 136 + k) = v;
  }
  __syncthreads();
  int wave = t >> 6, lane = t & 63;
  int m = lane & 15, quad = lane >> 4;
  int arow = wave * 16 + m;
  bfrag a[4];
#pragma unroll
  for (int ks = 0; ks < 4; ++ks)
    a[ks] = *(const bfrag*)(Alds + arow * 136 + ks * 32 + quad * 8);
  f32x4 acc[8];
#pragma unroll
  for (int nt = 0; nt < 8; ++nt) acc[nt] = (f32x4){0.f, 0.f, 0.f, 0.f};
#pragma unroll
  for (int nt = 0; nt < 8; ++nt) {
    int n = nt * 16 + m;
#pragma unroll
    for (int ks = 0; ks < 4; ++ks) {
      bfrag b = *(const bfrag*)(Wlds + n * 136 + ks * 32 + quad * 8);
      acc[nt] = __builtin_amdgcn_mfma_f32_16x16x32_bf16(a[ks], b, acc[nt], 0, 0, 0);
    }
  }
  // epilogue: C/D layout col=lane&15, row=quad*4+reg
#pragma unroll
  for (int nt = 0; nt < 8; ++nt) {
    int col = nt * 16 + m;
#pragma unroll
    for (int r = 0; r < 4; ++r) {
      int row = base + wave * 16 + quad * 4 + r;
      if (row < M) {
        float v = acc[nt][r];
        if (Cin)  v += Cin[(size_t)row * 128 + col];
        if (bias) { float b = bias[col]; v += degi ? b * (float)degi[row] : b; }
        if (relu) v = fmaxf(v, 0.f);
        if (OUTBF16) ((u16*)Cout)[(size_t)row * 128 + col] = f2b(v);
        else         ((float*)Cout)[(size_t)row * 128 + col] = v;
      }
    }
  }
}

// ---------- VALU GEMM (small K or small KO): C[M,KO] = A[M,KI]@W + extras ----------
template<int KI, int KO, bool ABF16, bool OUTBF16>
__global__ __launch_bounds__(128) void gemm_node(
    const void* __restrict__ A_, const float* __restrict__ W, void* __restrict__ Cout,
    const float* __restrict__ bias, const int* __restrict__ degi,
    const float* __restrict__ resid, int M, int relu) {
  const int ROWS = 8;
  int t = threadIdx.x;
  int base = blockIdx.x * ROWS;
  __shared__ float Al[ROWS * KI];
  for (int i = t; i < ROWS * KI; i += 128) {
    int r = i / KI, k = i - r * KI;
    int row = base + r;
    float v = 0.f;
    if (row < M) {
      if (ABF16) v = b2f(((const u16*)A_)[(size_t)row * KI + k]);
      else       v = ((const float*)A_)[(size_t)row * KI + k];
    }
    Al[i] = v;
  }
  __syncthreads();
  if (KO == 128) {
    float acc[ROWS];
#pragma unroll
    for (int r = 0; r < ROWS; ++r) acc[r] = 0.f;
    for (int k = 0; k < KI; ++k) {
      float w = W[k * 128 + t];
#pragma unroll
      for (int r = 0; r < ROWS; ++r) acc[r] += Al[r * KI + k] * w;
    }
#pragma unroll
    for (int r = 0; r < ROWS; ++r) {
      int row = base + r;
      if (row >= M) break;
      float v = acc[r];
      if (bias)  { float b = bias[t]; v += degi ? b * (float)degi[row] : b; }
      if (resid) v += resid[(size_t)row * 128 + t];
      if (relu)  v = fmaxf(v, 0.f);
      if (OUTBF16) ((u16*)Cout)[(size_t)row * 128 + t] = f2b(v);
      else         ((float*)Cout)[(size_t)row * 128 + t] = v;
    }
  } else {  // KO == 16
    int r = t >> 4, u = t & 15;
    int row = base + r;
    float acc = 0.f;
    for (int k = 0; k < KI; ++k) acc += Al[r * KI + k] * W[k * 16 + u];
    if (row < M) {
      float v = acc;
      if (bias)  { float b = bias[u]; v += degi ? b * (float)degi[row] : b; }
      if (resid) v += resid[(size_t)row * 16 + u];
      if (relu)  v = fmaxf(v, 0.f);
      if (OUTBF16) ((u16*)Cout)[(size_t)row * 16 + u] = f2b(v);
      else         ((float*)Cout)[(size_t)row * 16 + u] = v;
    }
  }
}

// ---------- EA hidden-sum gather: Hsum[n] = sum_e relu(pb[n] + q[src] + ea@W1ea) ----------
__global__ __launch_bounds__(128) void ea_gather(
    const u16* __restrict__ pb, const u16* __restrict__ q,
    const float* __restrict__ w1ea /*[16,128]*/, const float* __restrict__ ea /*[E,16]*/,
    const int* __restrict__ rowptr, const int* __restrict__ col,
    const int* __restrict__ erow, u16* __restrict__ Hsum) {
  int node = blockIdx.x;
  int t = threadIdx.x;
  __shared__ float wl[16 * 128];
  for (int i = t; i < 16 * 128; i += 128) wl[i] = w1ea[i];
  __syncthreads();
  float pbv = b2f(pb[(size_t)node * 128 + t]);
  float acc = 0.f;
  int e1 = rowptr[node + 1];
  for (int e = rowptr[node]; e < e1; ++e) {
    int s = col[e];
    int r = erow[e];
    float qv = b2f(q[(size_t)s * 128 + t]);
    const float4* p = reinterpret_cast<const float4*>(ea + (size_t)r * 16);
    float4 a0 = p[0], a1 = p[1], a2 = p[2], a3 = p[3];
    float v[16] = {a0.x, a0.y, a0.z, a0.w, a1.x, a1.y, a1.z, a1.w,
                   a2.x, a2.y, a2.z, a2.w, a3.x, a3.y, a3.z, a3.w};
    float proj = 0.f;
#pragma unroll
    for (int k = 0; k < 16; ++k) proj += v[k] * wl[k * 128 + t];
    acc += fmaxf(pbv + qv + proj, 0.f);
  }
  Hsum[(size_t)node * 128 + t] = f2b(acc);
}

// ---------- TAG hop gather: out[n] = dis[n] * sum_e dis[src]*hk[src] ----------
__global__ __launch_bounds__(128) void tag_gather(
    const u16* __restrict__ hk, const float* __restrict__ dis,
    const int* __restrict__ rowptr, const int* __restrict__ col,
    u16* __restrict__ out) {
  int node = blockIdx.x;
  int t = threadIdx.x;
  float acc = 0.f;
  int e1 = rowptr[node + 1];
  for (int e = rowptr[node]; e < e1; ++e) {
    int s = col[e];
    acc += dis[s] * b2f(hk[(size_t)s * 128 + t]);
  }
  out[(size_t)node * 128 + t] = f2b(dis[node] * acc);
}

extern "C" void kernel_launch(void* const* d_in, const int* in_sizes, int n_in,
                              void* d_out, int out_size, void* d_ws, size_t ws_size,
                              hipStream_t stream) {
  const float* x      = (const float*)d_in[0];
  const float* mask   = (const float*)d_in[1];
  const float* ea     = (const float*)d_in[2];
  const int*   eidx   = (const int*)d_in[3];
  const float* m_w1   = (const float*)d_in[4];
  const float* m_b1   = (const float*)d_in[5];
  const float* m_w2   = (const float*)d_in[6];
  const float* m_b2   = (const float*)d_in[7];
  const float* ea0_w1 = (const float*)d_in[8];
  const float* ea0_b1 = (const float*)d_in[9];
  const float* ea0_w2 = (const float*)d_in[10];
  const float* ea0_b2 = (const float*)d_in[11];
  const float* tag0_w = (const float*)d_in[12];
  const float* tag0_b = (const float*)d_in[13];
  const float* ea1_w1 = (const float*)d_in[14];
  const float* ea1_b1 = (const float*)d_in[15];
  const float* ea1_w2 = (const float*)d_in[16];
  const float* ea1_b2 = (const float*)d_in[17];
  const float* tag1_w = (const float*)d_in[18];
  const float* tag1_b = (const float*)d_in[19];
  const float* ea2_w1 = (const float*)d_in[20];
  const float* ea2_b1 = (const float*)d_in[21];
  const float* ea2_w2 = (const float*)d_in[22];
  const float* ea2_b2 = (const float*)d_in[23];

  const int N = in_sizes[0] / 16;   // 20000
  const int E = in_sizes[2] / 16;   // 160000
  const int E2 = 2 * E;

  // ---- workspace carve (256B-aligned); ~30 MB ----
  char* w = (char*)d_ws;
  auto alloc = [&](size_t bytes) { char* p = w; w += (bytes + 255) & ~(size_t)255; return p; };
  int*   degi   = (int*)alloc((size_t)N * 4);
  int*   cursor = (int*)alloc((size_t)N * 4);
  int*   rowptr = (int*)alloc((size_t)(N + 1) * 4);
  float* dis    = (float*)alloc((size_t)N * 4);
  int*   col    = (int*)alloc((size_t)E2 * 4);
  int*   erow   = (int*)alloc((size_t)E2 * 4);
  float* h16    = (float*)alloc((size_t)N * 16 * 4);
  float* Hf     = (float*)alloc((size_t)N * 128 * 4);   // fp32 acc buffer
  u16*   X0     = (u16*)alloc((size_t)N * 128 * 2);
  u16*   X1     = (u16*)alloc((size_t)N * 128 * 2);
  u16*   X2     = (u16*)alloc((size_t)N * 128 * 2);
  u16*   Wt     = (u16*)alloc((size_t)14 * 16384 * 2);  // transposed bf16 weights
  (void)ws_size; (void)n_in; (void)out_size;

  // ---- weight prep + CSR build ----
  hipMemsetAsync(degi, 0, (size_t)N * 4, stream);
  hipMemsetAsync(cursor, 0, (size_t)N * 4, stream);
  prep_wt<<<112, 256, 0, stream>>>(ea0_w2, tag0_w, ea1_w1, ea1_w2, tag1_w, ea2_w1, Wt);
  count_deg<<<(E + 255) / 256, 256, 0, stream>>>(eidx, degi, E);
  csr_scan<<<1, 1024, 0, stream>>>(degi, rowptr, dis, N);
  fill_csr<<<(E2 + 255) / 256, 256, 0, stream>>>(eidx, rowptr, cursor, col, erow, E);

  const int gb = (N + 7) / 8;          // VALU gemm blocks
  const int gm = (N + 63) / 64;        // MFMA gemm blocks
  u16* WT_ea0w2  = Wt + 0 * 16384;
  u16* WT_tag0   = Wt + 1 * 16384;
  u16* WT_ea1d   = Wt + 5 * 16384;
  u16* WT_ea1s   = Wt + 6 * 16384;
  u16* WT_ea1w2  = Wt + 7 * 16384;
  u16* WT_tag1   = Wt + 8 * 16384;
  u16* WT_ea2d   = Wt + 12 * 16384;
  u16* WT_ea2s   = Wt + 13 * 16384;

  // ---- mask MLP + residual: h16 = relu(mask@m_w1+b1)@m_w2 + b2 + x  (fp32 VALU) ----
  gemm_node<16, 128, false, false><<<gb, 128, 0, stream>>>(mask, m_w1, Hf, m_b1, nullptr, nullptr, N, 1);
  gemm_node<128, 16, false, false><<<gb, 128, 0, stream>>>(Hf, m_w2, h16, m_b2, nullptr, x, N, 0);

  // ---- EA0: pb/q via VALU (KI=16), gather, w2 via MFMA ----
  gemm_node<16, 128, false, true><<<gb, 128, 0, stream>>>(h16, ea0_w1, X0, ea0_b1, nullptr, nullptr, N, 0);
  gemm_node<16, 128, false, true><<<gb, 128, 0, stream>>>(h16, ea0_w1 + 16 * 128, X1, nullptr, nullptr, nullptr, N, 0);
  ea_gather<<<N, 128, 0, stream>>>(X0, X1, ea0_w1 + 32 * 128, ea, rowptr, col, erow, X2);
  gemm_mfma<true><<<gm, 256, 0, stream>>>(X2, WT_ea0w2, X0, nullptr, ea0_b2, degi, N, 1);   // h1 -> X0

  // ---- TAG0 ----
  gemm_mfma<false><<<gm, 256, 0, stream>>>(X0, WT_tag0, Hf, nullptr, nullptr, nullptr, N, 0);
  tag_gather<<<N, 128, 0, stream>>>(X0, dis, rowptr, col, X1);
  gemm_mfma<false><<<gm, 256, 0, stream>>>(X1, WT_tag0 + 16384, Hf, Hf, nullptr, nullptr, N, 0);
  tag_gather<<<N, 128, 0, stream>>>(X1, dis, rowptr, col, X2);
  gemm_mfma<false><<<gm, 256, 0, stream>>>(X2, WT_tag0 + 2 * 16384, Hf, Hf, nullptr, nullptr, N, 0);
  tag_gather<<<N, 128, 0, stream>>>(X2, dis, rowptr, col, X1);
  gemm_mfma<true><<<gm, 256, 0, stream>>>(X1, WT_tag0 + 3 * 16384, X0, Hf, tag0_b, nullptr, N, 1);  // h2 -> X0

  // ---- EA1 ----
  gemm_mfma<true><<<gm, 256, 0, stream>>>(X0, WT_ea1d, X1, nullptr, ea1_b1, nullptr, N, 0);   // pb
  gemm_mfma<true><<<gm, 256, 0, stream>>>(X0, WT_ea1s, X2, nullptr, nullptr, nullptr, N, 0);  // q
  ea_gather<<<N, 128, 0, stream>>>(X1, X2, ea1_w1 + 256 * 128, ea, rowptr, col, erow, X0);
  gemm_mfma<true><<<gm, 256, 0, stream>>>(X0, WT_ea1w2, X1, nullptr, ea1_b2, degi, N, 1);     // h3 -> X1

  // ---- TAG1 ----
  gemm_mfma<false><<<gm, 256, 0, stream>>>(X1, WT_tag1, Hf, nullptr, nullptr, nullptr, N, 0);
  tag_gather<<<N, 128, 0, stream>>>(X1, dis, rowptr, col, X0);
  gemm_mfma<false><<<gm, 256, 0, stream>>>(X0, WT_tag1 + 16384, Hf, Hf, nullptr, nullptr, N, 0);
  tag_gather<<<N, 128, 0, stream>>>(X0, dis, rowptr, col, X2);
  gemm_mfma<false><<<gm, 256, 0, stream>>>(X2, WT_tag1 + 2 * 16384, Hf, Hf, nullptr, nullptr, N, 0);
  tag_gather<<<N, 128, 0, stream>>>(X2, dis, rowptr, col, X0);
  gemm_mfma<true><<<gm, 256, 0, stream>>>(X0, WT_tag1 + 3 * 16384, X1, Hf, tag1_b, nullptr, N, 1);  // h4 -> X1

  // ---- EA2 (final, out 16, fp32) ----
  gemm_mfma<true><<<gm, 256, 0, stream>>>(X1, WT_ea2d, X0, nullptr, ea2_b1, nullptr, N, 0);   // pb
  gemm_mfma<true><<<gm, 256, 0, stream>>>(X1, WT_ea2s, X2, nullptr, nullptr, nullptr, N, 0);  // q
  ea_gather<<<N, 128, 0, stream>>>(X0, X2, ea2_w1 + 256 * 128, ea, rowptr, col, erow, X1);
  gemm_node<128, 16, true, false><<<gb, 128, 0, stream>>>(X1, ea2_w2, (float*)d_out, ea2_b2, degi, nullptr, N, 0);
}

// Round 4
// 731.377 us; speedup vs baseline: 1.2960x; 1.0703x over previous
//
#include <hip/hip_runtime.h>

typedef unsigned short u16;
typedef unsigned int u32;

using bfrag = __attribute__((ext_vector_type(8))) short;   // 8 bf16 (4 VGPRs)
using f32x4 = __attribute__((ext_vector_type(4))) float;   // 4 fp32 acc

// ---------- bf16 helpers ----------
__device__ __forceinline__ float b2f(u16 u) {
  union { u32 i; float f; } c; c.i = ((u32)u) << 16; return c.f;
}
__device__ __forceinline__ float bflo(u32 u) { union { u32 i; float f; } c; c.i = u << 16; return c.f; }
__device__ __forceinline__ float bfhi(u32 u) { union { u32 i; float f; } c; c.i = u & 0xffff0000u; return c.f; }
__device__ __forceinline__ u16 f2b(float f) {  // round-to-nearest-even
  union { float f; u32 i; } c; c.f = f;
  u32 x = c.i;
  u32 r = x + 0x7fffu + ((x >> 16) & 1u);
  return (u16)(r >> 16);
}

// ---------- CSR build ----------
__global__ __launch_bounds__(256) void count_deg(const int* __restrict__ eidx,
                                                 int* __restrict__ degi, int E) {
  int e = blockIdx.x * 256 + threadIdx.x;
  if (e >= E) return;
  atomicAdd(&degi[eidx[E + e]], 1);
  atomicAdd(&degi[eidx[e]], 1);
}

__global__ __launch_bounds__(1024) void csr_scan(const int* __restrict__ degi,
                                                 int* __restrict__ rowptr,
                                                 float* __restrict__ dis, int n) {
  __shared__ int sums[1024];
  int tid = threadIdx.x;
  const int CH = (n + 1023) / 1024;
  int base = tid * CH;
  int s = 0;
  for (int i = 0; i < CH; ++i) { int j = base + i; if (j < n) s += degi[j]; }
  sums[tid] = s;
  __syncthreads();
  for (int off = 1; off < 1024; off <<= 1) {
    int v = sums[tid];
    int add = (tid >= off) ? sums[tid - off] : 0;
    __syncthreads();
    sums[tid] = v + add;
    __syncthreads();
  }
  int run = sums[tid] - s;
  for (int i = 0; i < CH; ++i) {
    int j = base + i;
    if (j < n) { rowptr[j] = run; run += degi[j]; }
  }
  if (tid == 1023) rowptr[n] = sums[1023];
  for (int j = tid; j < n; j += 1024) {
    int d = degi[j];
    dis[j] = d > 0 ? rsqrtf((float)d) : 0.0f;
  }
}

__global__ __launch_bounds__(256) void fill_csr(const int* __restrict__ eidx,
                                                const int* __restrict__ rowptr,
                                                int* __restrict__ cursor,
                                                int* __restrict__ col,
                                                int* __restrict__ erow, int E) {
  int i = blockIdx.x * 256 + threadIdx.x;
  int E2 = 2 * E;
  if (i >= E2) return;
  int e = (i < E) ? i : i - E;
  int s, d;
  if (i < E) { s = eidx[e]; d = eidx[E + e]; }
  else       { s = eidx[E + e]; d = eidx[e]; }
  int pos = rowptr[d] + atomicAdd(&cursor[d], 1);
  col[pos] = s;
  erow[pos] = e;
}

// ---------- weight prep: fp32 [128k][128n] -> bf16 [128n][128k] in workspace ----------
__global__ __launch_bounds__(256) void prep_wt(
    const float* __restrict__ ea0_w2, const float* __restrict__ tag0_w,
    const float* __restrict__ ea1_w1, const float* __restrict__ ea1_w2,
    const float* __restrict__ tag1_w, const float* __restrict__ ea2_w1,
    u16* __restrict__ Wt) {
  int mat = blockIdx.x >> 3, chunk = blockIdx.x & 7;
  const float* src;
  if      (mat == 0)  src = ea0_w2;
  else if (mat <= 4)  src = tag0_w + (mat - 1) * 16384;
  else if (mat == 5)  src = ea1_w1;
  else if (mat == 6)  src = ea1_w1 + 16384;
  else if (mat == 7)  src = ea1_w2;
  else if (mat <= 11) src = tag1_w + (mat - 8) * 16384;
  else if (mat == 12) src = ea2_w1;
  else                src = ea2_w1 + 16384;
  u16* dst = Wt + mat * 16384;
  int t = threadIdx.x;
  for (int i = 0; i < 8; ++i) {
    int idx = chunk * 2048 + i * 256 + t;
    int k = idx >> 7, n = idx & 127;
    dst[n * 128 + k] = f2b(src[idx]);
  }
}

// ---------- MFMA GEMM: C[M,128] = A[M,128]bf16 @ W[128,128] (+Cin +bias/deg*bias +relu) ----------
template<bool OUTBF16>
__global__ __launch_bounds__(256) void gemm_mfma(
    const u16* __restrict__ A, const u16* __restrict__ Wt,
    void* __restrict__ Cout, const float* __restrict__ Cin,
    const float* __restrict__ bias, const int* __restrict__ degi,
    int M, int relu) {
  __shared__ u16 Alds[64 * 136];
  __shared__ u16 Wlds[128 * 136];
  int t = threadIdx.x;
  int base = blockIdx.x * 64;
#pragma unroll
  for (int i = 0; i < 8; ++i) {
    int idx = (i * 256 + t) * 8;
    int n = idx >> 7, k = idx & 127;
    uint4 v = *(const uint4*)(Wt + idx);
    *(uint4*)(Wlds + n * 136 + k) = v;
  }
#pragma unroll
  for (int i = 0; i < 4; ++i) {
    int idx = (i * 256 + t) * 8;
    int r = idx >> 7, k = idx & 127;
    int row = base + r;
    uint4 v = make_uint4(0, 0, 0, 0);
    if (row < M) v = *(const uint4*)(A + (size_t)row * 128 + k);
    *(uint4*)(Alds + r * 136 + k) = v;
  }
  __syncthreads();
  int wave = t >> 6, lane = t & 63;
  int m = lane & 15, quad = lane >> 4;
  int arow = wave * 16 + m;
  bfrag a[4];
#pragma unroll
  for (int ks = 0; ks < 4; ++ks)
    a[ks] = *(const bfrag*)(Alds + arow * 136 + ks * 32 + quad * 8);
  f32x4 acc[8];
#pragma unroll
  for (int nt = 0; nt < 8; ++nt) acc[nt] = (f32x4){0.f, 0.f, 0.f, 0.f};
#pragma unroll
  for (int nt = 0; nt < 8; ++nt) {
    int n = nt * 16 + m;
#pragma unroll
    for (int ks = 0; ks < 4; ++ks) {
      bfrag b = *(const bfrag*)(Wlds + n * 136 + ks * 32 + quad * 8);
      acc[nt] = __builtin_amdgcn_mfma_f32_16x16x32_bf16(a[ks], b, acc[nt], 0, 0, 0);
    }
  }
#pragma unroll
  for (int nt = 0; nt < 8; ++nt) {
    int col = nt * 16 + m;
#pragma unroll
    for (int r = 0; r < 4; ++r) {
      int row = base + wave * 16 + quad * 4 + r;
      if (row < M) {
        float v = acc[nt][r];
        if (Cin)  v += Cin[(size_t)row * 128 + col];
        if (bias) { float b = bias[col]; v += degi ? b * (float)degi[row] : b; }
        if (relu) v = fmaxf(v, 0.f);
        if (OUTBF16) ((u16*)Cout)[(size_t)row * 128 + col] = f2b(v);
        else         ((float*)Cout)[(size_t)row * 128 + col] = v;
      }
    }
  }
}

// ---------- VALU GEMM (small K or small KO) ----------
template<int KI, int KO, bool ABF16, bool OUTBF16>
__global__ __launch_bounds__(128) void gemm_node(
    const void* __restrict__ A_, const float* __restrict__ W, void* __restrict__ Cout,
    const float* __restrict__ bias, const int* __restrict__ degi,
    const float* __restrict__ resid, int M, int relu) {
  const int ROWS = 8;
  int t = threadIdx.x;
  int base = blockIdx.x * ROWS;
  __shared__ float Al[ROWS * KI];
  for (int i = t; i < ROWS * KI; i += 128) {
    int r = i / KI, k = i - r * KI;
    int row = base + r;
    float v = 0.f;
    if (row < M) {
      if (ABF16) v = b2f(((const u16*)A_)[(size_t)row * KI + k]);
      else       v = ((const float*)A_)[(size_t)row * KI + k];
    }
    Al[i] = v;
  }
  __syncthreads();
  if (KO == 128) {
    float acc[ROWS];
#pragma unroll
    for (int r = 0; r < ROWS; ++r) acc[r] = 0.f;
    for (int k = 0; k < KI; ++k) {
      float w = W[k * 128 + t];
#pragma unroll
      for (int r = 0; r < ROWS; ++r) acc[r] += Al[r * KI + k] * w;
    }
#pragma unroll
    for (int r = 0; r < ROWS; ++r) {
      int row = base + r;
      if (row >= M) break;
      float v = acc[r];
      if (bias)  { float b = bias[t]; v += degi ? b * (float)degi[row] : b; }
      if (resid) v += resid[(size_t)row * 128 + t];
      if (relu)  v = fmaxf(v, 0.f);
      if (OUTBF16) ((u16*)Cout)[(size_t)row * 128 + t] = f2b(v);
      else         ((float*)Cout)[(size_t)row * 128 + t] = v;
    }
  } else {
    int r = t >> 4, u = t & 15;
    int row = base + r;
    float acc = 0.f;
    for (int k = 0; k < KI; ++k) acc += Al[r * KI + k] * W[k * 16 + u];
    if (row < M) {
      float v = acc;
      if (bias)  { float b = bias[u]; v += degi ? b * (float)degi[row] : b; }
      if (resid) v += resid[(size_t)row * 16 + u];
      if (relu)  v = fmaxf(v, 0.f);
      if (OUTBF16) ((u16*)Cout)[(size_t)row * 16 + u] = f2b(v);
      else         ((float*)Cout)[(size_t)row * 16 + u] = v;
    }
  }
}

// ---------- EA gather v2: wave-per-node, 2 cols/lane, weights in VGPRs, ea via s_load ----------
__global__ __launch_bounds__(256) void ea_gather2(
    const u16* __restrict__ pb, const u16* __restrict__ q,
    const float* __restrict__ w1ea /*[16][128]*/, const float* __restrict__ ea /*[E,16]*/,
    const int* __restrict__ rowptr, const int* __restrict__ col,
    const int* __restrict__ erow, u16* __restrict__ Hsum, int N) {
  int wave = threadIdx.x >> 6, lane = threadIdx.x & 63;
  int node = blockIdx.x * 4 + wave;
  if (node >= N) return;
  // lane covers output cols 2*lane, 2*lane+1; w1ea columns held in VGPRs
  float w0[16], w1[16];
#pragma unroll
  for (int k = 0; k < 16; ++k) {
    w0[k] = w1ea[k * 128 + 2 * lane];
    w1[k] = w1ea[k * 128 + 2 * lane + 1];
  }
  u32 pbu = *(const u32*)(pb + (size_t)node * 128 + 2 * lane);
  float pb0 = bflo(pbu), pb1 = bfhi(pbu);
  float acc0 = 0.f, acc1 = 0.f;
  int e1 = rowptr[node + 1];
  for (int e = rowptr[node]; e < e1; ++e) {
    int s = __builtin_amdgcn_readfirstlane(col[e]);   // wave-uniform -> scalar
    int r = __builtin_amdgcn_readfirstlane(erow[e]);
    u32 qu = *(const u32*)(q + (size_t)s * 128 + 2 * lane);
    const float* er = ea + (size_t)r * 16;            // uniform base -> s_load path
    float p0 = pb0, p1 = pb1;
#pragma unroll
    for (int k = 0; k < 16; ++k) { float ev = er[k]; p0 += ev * w0[k]; p1 += ev * w1[k]; }
    p0 += bflo(qu); p1 += bfhi(qu);
    acc0 += fmaxf(p0, 0.f);
    acc1 += fmaxf(p1, 0.f);
  }
  u32 outv = ((u32)f2b(acc0)) | (((u32)f2b(acc1)) << 16);
  *(u32*)(Hsum + (size_t)node * 128 + 2 * lane) = outv;
}

// ---------- TAG gather v2: wave-per-node, 2 cols/lane ----------
__global__ __launch_bounds__(256) void tag_gather2(
    const u16* __restrict__ hk, const float* __restrict__ dis,
    const int* __restrict__ rowptr, const int* __restrict__ col,
    u16* __restrict__ out, int N) {
  int wave = threadIdx.x >> 6, lane = threadIdx.x & 63;
  int node = blockIdx.x * 4 + wave;
  if (node >= N) return;
  float acc0 = 0.f, acc1 = 0.f;
  int e1 = rowptr[node + 1];
  for (int e = rowptr[node]; e < e1; ++e) {
    int s = __builtin_amdgcn_readfirstlane(col[e]);
    float ds = dis[s];
    u32 hu = *(const u32*)(hk + (size_t)s * 128 + 2 * lane);
    acc0 += ds * bflo(hu);
    acc1 += ds * bfhi(hu);
  }
  float dn = dis[node];
  u32 outv = ((u32)f2b(dn * acc0)) | (((u32)f2b(dn * acc1)) << 16);
  *(u32*)(out + (size_t)node * 128 + 2 * lane) = outv;
}

extern "C" void kernel_launch(void* const* d_in, const int* in_sizes, int n_in,
                              void* d_out, int out_size, void* d_ws, size_t ws_size,
                              hipStream_t stream) {
  const float* x      = (const float*)d_in[0];
  const float* mask   = (const float*)d_in[1];
  const float* ea     = (const float*)d_in[2];
  const int*   eidx   = (const int*)d_in[3];
  const float* m_w1   = (const float*)d_in[4];
  const float* m_b1   = (const float*)d_in[5];
  const float* m_w2   = (const float*)d_in[6];
  const float* m_b2   = (const float*)d_in[7];
  const float* ea0_w1 = (const float*)d_in[8];
  const float* ea0_b1 = (const float*)d_in[9];
  const float* ea0_w2 = (const float*)d_in[10];
  const float* ea0_b2 = (const float*)d_in[11];
  const float* tag0_w = (const float*)d_in[12];
  const float* tag0_b = (const float*)d_in[13];
  const float* ea1_w1 = (const float*)d_in[14];
  const float* ea1_b1 = (const float*)d_in[15];
  const float* ea1_w2 = (const float*)d_in[16];
  const float* ea1_b2 = (const float*)d_in[17];
  const float* tag1_w = (const float*)d_in[18];
  const float* tag1_b = (const float*)d_in[19];
  const float* ea2_w1 = (const float*)d_in[20];
  const float* ea2_b1 = (const float*)d_in[21];
  const float* ea2_w2 = (const float*)d_in[22];
  const float* ea2_b2 = (const float*)d_in[23];

  const int N = in_sizes[0] / 16;   // 20000
  const int E = in_sizes[2] / 16;   // 160000
  const int E2 = 2 * E;

  char* w = (char*)d_ws;
  auto alloc = [&](size_t bytes) { char* p = w; w += (bytes + 255) & ~(size_t)255; return p; };
  int*   degi   = (int*)alloc((size_t)N * 4);
  int*   cursor = (int*)alloc((size_t)N * 4);
  int*   rowptr = (int*)alloc((size_t)(N + 1) * 4);
  float* dis    = (float*)alloc((size_t)N * 4);
  int*   col    = (int*)alloc((size_t)E2 * 4);
  int*   erow   = (int*)alloc((size_t)E2 * 4);
  float* h16    = (float*)alloc((size_t)N * 16 * 4);
  float* Hf     = (float*)alloc((size_t)N * 128 * 4);
  u16*   X0     = (u16*)alloc((size_t)N * 128 * 2);
  u16*   X1     = (u16*)alloc((size_t)N * 128 * 2);
  u16*   X2     = (u16*)alloc((size_t)N * 128 * 2);
  u16*   Wt     = (u16*)alloc((size_t)14 * 16384 * 2);
  (void)ws_size; (void)n_in; (void)out_size;

  hipMemsetAsync(degi, 0, (size_t)N * 4, stream);
  hipMemsetAsync(cursor, 0, (size_t)N * 4, stream);
  prep_wt<<<112, 256, 0, stream>>>(ea0_w2, tag0_w, ea1_w1, ea1_w2, tag1_w, ea2_w1, Wt);
  count_deg<<<(E + 255) / 256, 256, 0, stream>>>(eidx, degi, E);
  csr_scan<<<1, 1024, 0, stream>>>(degi, rowptr, dis, N);
  fill_csr<<<(E2 + 255) / 256, 256, 0, stream>>>(eidx, rowptr, cursor, col, erow, E);

  const int gb = (N + 7) / 8;          // VALU gemm blocks
  const int gm = (N + 63) / 64;        // MFMA gemm blocks
  const int g4 = (N + 3) / 4;          // gather blocks (4 waves = 4 nodes)
  u16* WT_ea0w2  = Wt + 0 * 16384;
  u16* WT_tag0   = Wt + 1 * 16384;
  u16* WT_ea1d   = Wt + 5 * 16384;
  u16* WT_ea1s   = Wt + 6 * 16384;
  u16* WT_ea1w2  = Wt + 7 * 16384;
  u16* WT_tag1   = Wt + 8 * 16384;
  u16* WT_ea2d   = Wt + 12 * 16384;
  u16* WT_ea2s   = Wt + 13 * 16384;

  // ---- mask MLP + residual ----
  gemm_node<16, 128, false, false><<<gb, 128, 0, stream>>>(mask, m_w1, Hf, m_b1, nullptr, nullptr, N, 1);
  gemm_node<128, 16, false, false><<<gb, 128, 0, stream>>>(Hf, m_w2, h16, m_b2, nullptr, x, N, 0);

  // ---- EA0 ----
  gemm_node<16, 128, false, true><<<gb, 128, 0, stream>>>(h16, ea0_w1, X0, ea0_b1, nullptr, nullptr, N, 0);
  gemm_node<16, 128, false, true><<<gb, 128, 0, stream>>>(h16, ea0_w1 + 16 * 128, X1, nullptr, nullptr, nullptr, N, 0);
  ea_gather2<<<g4, 256, 0, stream>>>(X0, X1, ea0_w1 + 32 * 128, ea, rowptr, col, erow, X2, N);
  gemm_mfma<true><<<gm, 256, 0, stream>>>(X2, WT_ea0w2, X0, nullptr, ea0_b2, degi, N, 1);   // h1 -> X0

  // ---- TAG0 ----
  gemm_mfma<false><<<gm, 256, 0, stream>>>(X0, WT_tag0, Hf, nullptr, nullptr, nullptr, N, 0);
  tag_gather2<<<g4, 256, 0, stream>>>(X0, dis, rowptr, col, X1, N);
  gemm_mfma<false><<<gm, 256, 0, stream>>>(X1, WT_tag0 + 16384, Hf, Hf, nullptr, nullptr, N, 0);
  tag_gather2<<<g4, 256, 0, stream>>>(X1, dis, rowptr, col, X2, N);
  gemm_mfma<false><<<gm, 256, 0, stream>>>(X2, WT_tag0 + 2 * 16384, Hf, Hf, nullptr, nullptr, N, 0);
  tag_gather2<<<g4, 256, 0, stream>>>(X2, dis, rowptr, col, X1, N);
  gemm_mfma<true><<<gm, 256, 0, stream>>>(X1, WT_tag0 + 3 * 16384, X0, Hf, tag0_b, nullptr, N, 1);  // h2 -> X0

  // ---- EA1 ----
  gemm_mfma<true><<<gm, 256, 0, stream>>>(X0, WT_ea1d, X1, nullptr, ea1_b1, nullptr, N, 0);
  gemm_mfma<true><<<gm, 256, 0, stream>>>(X0, WT_ea1s, X2, nullptr, nullptr, nullptr, N, 0);
  ea_gather2<<<g4, 256, 0, stream>>>(X1, X2, ea1_w1 + 256 * 128, ea, rowptr, col, erow, X0, N);
  gemm_mfma<true><<<gm, 256, 0, stream>>>(X0, WT_ea1w2, X1, nullptr, ea1_b2, degi, N, 1);     // h3 -> X1

  // ---- TAG1 ----
  gemm_mfma<false><<<gm, 256, 0, stream>>>(X1, WT_tag1, Hf, nullptr, nullptr, nullptr, N, 0);
  tag_gather2<<<g4, 256, 0, stream>>>(X1, dis, rowptr, col, X0, N);
  gemm_mfma<false><<<gm, 256, 0, stream>>>(X0, WT_tag1 + 16384, Hf, Hf, nullptr, nullptr, N, 0);
  tag_gather2<<<g4, 256, 0, stream>>>(X0, dis, rowptr, col, X2, N);
  gemm_mfma<false><<<gm, 256, 0, stream>>>(X2, WT_tag1 + 2 * 16384, Hf, Hf, nullptr, nullptr, N, 0);
  tag_gather2<<<g4, 256, 0, stream>>>(X2, dis, rowptr, col, X0, N);
  gemm_mfma<true><<<gm, 256, 0, stream>>>(X0, WT_tag1 + 3 * 16384, X1, Hf, tag1_b, nullptr, N, 1);  // h4 -> X1

  // ---- EA2 ----
  gemm_mfma<true><<<gm, 256, 0, stream>>>(X1, WT_ea2d, X0, nullptr, ea2_b1, nullptr, N, 0);
  gemm_mfma<true><<<gm, 256, 0, stream>>>(X1, WT_ea2s, X2, nullptr, nullptr, nullptr, N, 0);
  ea_gather2<<<g4, 256, 0, stream>>>(X0, X2, ea2_w1 + 256 * 128, ea, rowptr, col, erow, X1, N);
  gemm_node<128, 16, true, false><<<gb, 128, 0, stream>>>(X1, ea2_w2, (float*)d_out, ea2_b2, degi, nullptr, N, 0);
}

// Round 5
// 594.837 us; speedup vs baseline: 1.5934x; 1.2295x over previous
//
#include <hip/hip_runtime.h>

typedef unsigned short u16;
typedef unsigned int u32;

using bfrag = __attribute__((ext_vector_type(8))) short;   // 8 bf16 (4 VGPRs)
using f32x4 = __attribute__((ext_vector_type(4))) float;   // 4 fp32 acc

// ---------- bf16 helpers ----------
__device__ __forceinline__ float b2f(u16 u) {
  union { u32 i; float f; } c; c.i = ((u32)u) << 16; return c.f;
}
__device__ __forceinline__ float bflo(u32 u) { union { u32 i; float f; } c; c.i = u << 16; return c.f; }
__device__ __forceinline__ float bfhi(u32 u) { union { u32 i; float f; } c; c.i = u & 0xffff0000u; return c.f; }
__device__ __forceinline__ u16 f2b(float f) {  // round-to-nearest-even
  union { float f; u32 i; } c; c.f = f;
  u32 x = c.i;
  u32 r = x + 0x7fffu + ((x >> 16) & 1u);
  return (u16)(r >> 16);
}

// ---------- CSR build ----------
__global__ __launch_bounds__(256) void count_deg(const int* __restrict__ eidx,
                                                 int* __restrict__ degi, int E) {
  int e = blockIdx.x * 256 + threadIdx.x;
  if (e >= E) return;
  atomicAdd(&degi[eidx[E + e]], 1);
  atomicAdd(&degi[eidx[e]], 1);
}

__global__ __launch_bounds__(1024) void csr_scan(const int* __restrict__ degi,
                                                 int* __restrict__ rowptr,
                                                 float* __restrict__ dis, int n) {
  __shared__ int sums[1024];
  int tid = threadIdx.x;
  const int CH = (n + 1023) / 1024;
  int base = tid * CH;
  int s = 0;
  for (int i = 0; i < CH; ++i) { int j = base + i; if (j < n) s += degi[j]; }
  sums[tid] = s;
  __syncthreads();
  for (int off = 1; off < 1024; off <<= 1) {
    int v = sums[tid];
    int add = (tid >= off) ? sums[tid - off] : 0;
    __syncthreads();
    sums[tid] = v + add;
    __syncthreads();
  }
  int run = sums[tid] - s;
  for (int i = 0; i < CH; ++i) {
    int j = base + i;
    if (j < n) { rowptr[j] = run; run += degi[j]; }
  }
  if (tid == 1023) rowptr[n] = sums[1023];
  for (int j = tid; j < n; j += 1024) {
    int d = degi[j];
    dis[j] = d > 0 ? rsqrtf((float)d) : 0.0f;
  }
}

// fill CSR writing packed edge records directly:
//   cw[pos] = (src, bits(dis[src]))  for TAG;  ce[pos] = (src, erow) for EA
__global__ __launch_bounds__(256) void fill_csr(const int* __restrict__ eidx,
                                                const int* __restrict__ rowptr,
                                                int* __restrict__ cursor,
                                                const float* __restrict__ dis,
                                                int2* __restrict__ cw,
                                                int2* __restrict__ ce, int E) {
  int i = blockIdx.x * 256 + threadIdx.x;
  int E2 = 2 * E;
  if (i >= E2) return;
  int e = (i < E) ? i : i - E;
  int s, d;
  if (i < E) { s = eidx[e]; d = eidx[E + e]; }
  else       { s = eidx[E + e]; d = eidx[e]; }
  int pos = rowptr[d] + atomicAdd(&cursor[d], 1);
  cw[pos] = make_int2(s, __float_as_int(dis[s]));
  ce[pos] = make_int2(s, e);
}

// ---------- weight prep: fp32 [128k][128n] -> bf16 [128n][128k] ----------
__global__ __launch_bounds__(256) void prep_wt(
    const float* __restrict__ ea0_w2, const float* __restrict__ tag0_w,
    const float* __restrict__ ea1_w1, const float* __restrict__ ea1_w2,
    const float* __restrict__ tag1_w, const float* __restrict__ ea2_w1,
    u16* __restrict__ Wt) {
  int mat = blockIdx.x >> 3, chunk = blockIdx.x & 7;
  const float* src;
  if      (mat == 0)  src = ea0_w2;
  else if (mat <= 4)  src = tag0_w + (mat - 1) * 16384;
  else if (mat == 5)  src = ea1_w1;
  else if (mat == 6)  src = ea1_w1 + 16384;
  else if (mat == 7)  src = ea1_w2;
  else if (mat <= 11) src = tag1_w + (mat - 8) * 16384;
  else if (mat == 12) src = ea2_w1;
  else                src = ea2_w1 + 16384;
  u16* dst = Wt + mat * 16384;
  int t = threadIdx.x;
  for (int i = 0; i < 8; ++i) {
    int idx = chunk * 2048 + i * 256 + t;
    int k = idx >> 7, n = idx & 127;
    dst[n * 128 + k] = f2b(src[idx]);
  }
}

// ---------- MFMA GEMM: C[M,128] = A[M,128]bf16 @ W (+Cin +bias/deg*bias +relu) ----------
template<bool OUTBF16>
__global__ __launch_bounds__(256) void gemm_mfma(
    const u16* __restrict__ A, const u16* __restrict__ Wt,
    void* __restrict__ Cout, const float* __restrict__ Cin,
    const float* __restrict__ bias, const int* __restrict__ degi,
    int M, int relu) {
  __shared__ u16 Alds[64 * 136];
  __shared__ u16 Wlds[128 * 136];
  int t = threadIdx.x;
  int base = blockIdx.x * 64;
#pragma unroll
  for (int i = 0; i < 8; ++i) {
    int idx = (i * 256 + t) * 8;
    int n = idx >> 7, k = idx & 127;
    uint4 v = *(const uint4*)(Wt + idx);
    *(uint4*)(Wlds + n * 136 + k) = v;
  }
#pragma unroll
  for (int i = 0; i < 4; ++i) {
    int idx = (i * 256 + t) * 8;
    int r = idx >> 7, k = idx & 127;
    int row = base + r;
    uint4 v = make_uint4(0, 0, 0, 0);
    if (row < M) v = *(const uint4*)(A + (size_t)row * 128 + k);
    *(uint4*)(Alds + r * 136 + k) = v;
  }
  __syncthreads();
  int wave = t >> 6, lane = t & 63;
  int m = lane & 15, quad = lane >> 4;
  int arow = wave * 16 + m;
  bfrag a[4];
#pragma unroll
  for (int ks = 0; ks < 4; ++ks)
    a[ks] = *(const bfrag*)(Alds + arow * 136 + ks * 32 + quad * 8);
  f32x4 acc[8];
#pragma unroll
  for (int nt = 0; nt < 8; ++nt) acc[nt] = (f32x4){0.f, 0.f, 0.f, 0.f};
#pragma unroll
  for (int nt = 0; nt < 8; ++nt) {
    int n = nt * 16 + m;
#pragma unroll
    for (int ks = 0; ks < 4; ++ks) {
      bfrag b = *(const bfrag*)(Wlds + n * 136 + ks * 32 + quad * 8);
      acc[nt] = __builtin_amdgcn_mfma_f32_16x16x32_bf16(a[ks], b, acc[nt], 0, 0, 0);
    }
  }
#pragma unroll
  for (int nt = 0; nt < 8; ++nt) {
    int col = nt * 16 + m;
#pragma unroll
    for (int r = 0; r < 4; ++r) {
      int row = base + wave * 16 + quad * 4 + r;
      if (row < M) {
        float v = acc[nt][r];
        if (Cin)  v += Cin[(size_t)row * 128 + col];
        if (bias) { float b = bias[col]; v += degi ? b * (float)degi[row] : b; }
        if (relu) v = fmaxf(v, 0.f);
        if (OUTBF16) ((u16*)Cout)[(size_t)row * 128 + col] = f2b(v);
        else         ((float*)Cout)[(size_t)row * 128 + col] = v;
      }
    }
  }
}

// ---------- dual MFMA GEMM: C0 = A@W0 + bias0, C1 = A@W1 (both bf16 out) ----------
__global__ __launch_bounds__(256) void gemm_mfma_dual(
    const u16* __restrict__ A, const u16* __restrict__ W0t, const u16* __restrict__ W1t,
    u16* __restrict__ C0, u16* __restrict__ C1, const float* __restrict__ bias0, int M) {
  __shared__ u16 Alds[64 * 136];
  __shared__ u16 Wlds[128 * 136];
  int t = threadIdx.x;
  int base = blockIdx.x * 64;
#pragma unroll
  for (int i = 0; i < 8; ++i) {
    int idx = (i * 256 + t) * 8;
    int n = idx >> 7, k = idx & 127;
    uint4 v = *(const uint4*)(W0t + idx);
    *(uint4*)(Wlds + n * 136 + k) = v;
  }
#pragma unroll
  for (int i = 0; i < 4; ++i) {
    int idx = (i * 256 + t) * 8;
    int r = idx >> 7, k = idx & 127;
    int row = base + r;
    uint4 v = make_uint4(0, 0, 0, 0);
    if (row < M) v = *(const uint4*)(A + (size_t)row * 128 + k);
    *(uint4*)(Alds + r * 136 + k) = v;
  }
  __syncthreads();
  int wave = t >> 6, lane = t & 63;
  int m = lane & 15, quad = lane >> 4;
  int arow = wave * 16 + m;
  bfrag a[4];
#pragma unroll
  for (int ks = 0; ks < 4; ++ks)
    a[ks] = *(const bfrag*)(Alds + arow * 136 + ks * 32 + quad * 8);
  f32x4 acc0[8], acc1[8];
#pragma unroll
  for (int nt = 0; nt < 8; ++nt) { acc0[nt] = (f32x4){0,0,0,0}; acc1[nt] = (f32x4){0,0,0,0}; }
#pragma unroll
  for (int nt = 0; nt < 8; ++nt) {
    int n = nt * 16 + m;
#pragma unroll
    for (int ks = 0; ks < 4; ++ks) {
      bfrag b = *(const bfrag*)(Wlds + n * 136 + ks * 32 + quad * 8);
      acc0[nt] = __builtin_amdgcn_mfma_f32_16x16x32_bf16(a[ks], b, acc0[nt], 0, 0, 0);
    }
  }
  __syncthreads();   // done reading W0
#pragma unroll
  for (int i = 0; i < 8; ++i) {
    int idx = (i * 256 + t) * 8;
    int n = idx >> 7, k = idx & 127;
    uint4 v = *(const uint4*)(W1t + idx);
    *(uint4*)(Wlds + n * 136 + k) = v;
  }
  __syncthreads();
#pragma unroll
  for (int nt = 0; nt < 8; ++nt) {
    int n = nt * 16 + m;
#pragma unroll
    for (int ks = 0; ks < 4; ++ks) {
      bfrag b = *(const bfrag*)(Wlds + n * 136 + ks * 32 + quad * 8);
      acc1[nt] = __builtin_amdgcn_mfma_f32_16x16x32_bf16(a[ks], b, acc1[nt], 0, 0, 0);
    }
  }
#pragma unroll
  for (int nt = 0; nt < 8; ++nt) {
    int col = nt * 16 + m;
#pragma unroll
    for (int r = 0; r < 4; ++r) {
      int row = base + wave * 16 + quad * 4 + r;
      if (row < M) {
        C0[(size_t)row * 128 + col] = f2b(acc0[nt][r] + bias0[col]);
        C1[(size_t)row * 128 + col] = f2b(acc1[nt][r]);
      }
    }
  }
}

// ---------- VALU GEMM (small K or small KO) ----------
template<int KI, int KO, bool ABF16, bool OUTBF16>
__global__ __launch_bounds__(128) void gemm_node(
    const void* __restrict__ A_, const float* __restrict__ W, void* __restrict__ Cout,
    const float* __restrict__ bias, const int* __restrict__ degi,
    const float* __restrict__ resid, int M, int relu) {
  const int ROWS = 8;
  int t = threadIdx.x;
  int base = blockIdx.x * ROWS;
  __shared__ float Al[ROWS * KI];
  for (int i = t; i < ROWS * KI; i += 128) {
    int r = i / KI, k = i - r * KI;
    int row = base + r;
    float v = 0.f;
    if (row < M) {
      if (ABF16) v = b2f(((const u16*)A_)[(size_t)row * KI + k]);
      else       v = ((const float*)A_)[(size_t)row * KI + k];
    }
    Al[i] = v;
  }
  __syncthreads();
  if (KO == 128) {
    float acc[ROWS];
#pragma unroll
    for (int r = 0; r < ROWS; ++r) acc[r] = 0.f;
    for (int k = 0; k < KI; ++k) {
      float w = W[k * 128 + t];
#pragma unroll
      for (int r = 0; r < ROWS; ++r) acc[r] += Al[r * KI + k] * w;
    }
#pragma unroll
    for (int r = 0; r < ROWS; ++r) {
      int row = base + r;
      if (row >= M) break;
      float v = acc[r];
      if (bias)  { float b = bias[t]; v += degi ? b * (float)degi[row] : b; }
      if (resid) v += resid[(size_t)row * 128 + t];
      if (relu)  v = fmaxf(v, 0.f);
      if (OUTBF16) ((u16*)Cout)[(size_t)row * 128 + t] = f2b(v);
      else         ((float*)Cout)[(size_t)row * 128 + t] = v;
    }
  } else {
    int r = t >> 4, u = t & 15;
    int row = base + r;
    float acc = 0.f;
    for (int k = 0; k < KI; ++k) acc += Al[r * KI + k] * W[k * 16 + u];
    if (row < M) {
      float v = acc;
      if (bias)  { float b = bias[u]; v += degi ? b * (float)degi[row] : b; }
      if (resid) v += resid[(size_t)row * 16 + u];
      if (relu)  v = fmaxf(v, 0.f);
      if (OUTBF16) ((u16*)Cout)[(size_t)row * 16 + u] = f2b(v);
      else         ((float*)Cout)[(size_t)row * 16 + u] = v;
    }
  }
}

// ---------- TAG gather v3: chunk preload + shfl broadcast + saddr loads ----------
__global__ __launch_bounds__(256) void tag_gather3(
    const u16* __restrict__ hk, const float* __restrict__ dis,
    const int* __restrict__ rowptr, const int2* __restrict__ cw,
    u16* __restrict__ out, int N) {
  int wave = threadIdx.x >> 6, lane = threadIdx.x & 63;
  int node = blockIdx.x * 4 + wave;
  if (node >= N) return;
  int e0 = rowptr[node];
  int deg = rowptr[node + 1] - e0;
  float a0 = 0.f, a1 = 0.f, b0 = 0.f, b1 = 0.f;
  for (int base = 0; base < deg; base += 64) {
    int2 v = make_int2(0, 0);
    if (base + lane < deg) v = cw[e0 + base + lane];
    int cnt = min(64, deg - base);
    int j = 0;
    for (; j + 2 <= cnt; j += 2) {
      int s0 = __builtin_amdgcn_readfirstlane(__shfl(v.x, j));
      int s1 = __builtin_amdgcn_readfirstlane(__shfl(v.x, j + 1));
      float w0 = __int_as_float(__shfl(v.y, j));
      float w1 = __int_as_float(__shfl(v.y, j + 1));
      u32 h0 = *(const u32*)(hk + (size_t)s0 * 128 + 2 * lane);
      u32 h1 = *(const u32*)(hk + (size_t)s1 * 128 + 2 * lane);
      a0 += w0 * bflo(h0); a1 += w0 * bfhi(h0);
      b0 += w1 * bflo(h1); b1 += w1 * bfhi(h1);
    }
    if (j < cnt) {
      int s0 = __builtin_amdgcn_readfirstlane(__shfl(v.x, j));
      float w0 = __int_as_float(__shfl(v.y, j));
      u32 h0 = *(const u32*)(hk + (size_t)s0 * 128 + 2 * lane);
      a0 += w0 * bflo(h0); a1 += w0 * bfhi(h0);
    }
  }
  float dn = dis[node];
  u32 outv = ((u32)f2b(dn * (a0 + b0))) | (((u32)f2b(dn * (a1 + b1))) << 16);
  *(u32*)(out + (size_t)node * 128 + 2 * lane) = outv;
}

// ---------- EA gather v3: chunk preload + shfl; w1ea columns in VGPRs; ea rows via s_load ----------
__global__ __launch_bounds__(256) void ea_gather3(
    const u16* __restrict__ pb, const u16* __restrict__ q,
    const float* __restrict__ w1ea /*[16][128]*/, const float* __restrict__ ea /*[E,16]*/,
    const int* __restrict__ rowptr, const int2* __restrict__ ce,
    u16* __restrict__ Hsum, int N) {
  int wave = threadIdx.x >> 6, lane = threadIdx.x & 63;
  int node = blockIdx.x * 4 + wave;
  if (node >= N) return;
  float w0[16], w1[16];
#pragma unroll
  for (int k = 0; k < 16; ++k) {
    w0[k] = w1ea[k * 128 + 2 * lane];
    w1[k] = w1ea[k * 128 + 2 * lane + 1];
  }
  u32 pbu = *(const u32*)(pb + (size_t)node * 128 + 2 * lane);
  float pb0 = bflo(pbu), pb1 = bfhi(pbu);
  float acc0 = 0.f, acc1 = 0.f;
  int e0 = rowptr[node];
  int deg = rowptr[node + 1] - e0;
  for (int base = 0; base < deg; base += 64) {
    int2 v = make_int2(0, 0);
    if (base + lane < deg) v = ce[e0 + base + lane];
    int cnt = min(64, deg - base);
    int j = 0;
    for (; j + 2 <= cnt; j += 2) {
      int s0 = __builtin_amdgcn_readfirstlane(__shfl(v.x, j));
      int r0 = __builtin_amdgcn_readfirstlane(__shfl(v.y, j));
      int s1 = __builtin_amdgcn_readfirstlane(__shfl(v.x, j + 1));
      int r1 = __builtin_amdgcn_readfirstlane(__shfl(v.y, j + 1));
      u32 q0 = *(const u32*)(q + (size_t)s0 * 128 + 2 * lane);
      u32 q1 = *(const u32*)(q + (size_t)s1 * 128 + 2 * lane);
      const float* er0 = ea + (size_t)r0 * 16;
      const float* er1 = ea + (size_t)r1 * 16;
      float p0 = pb0 + bflo(q0), p1 = pb1 + bfhi(q0);
      float t0 = pb0 + bflo(q1), t1 = pb1 + bfhi(q1);
#pragma unroll
      for (int k = 0; k < 16; ++k) {
        float e0v = er0[k], e1v = er1[k];
        p0 += e0v * w0[k]; p1 += e0v * w1[k];
        t0 += e1v * w0[k]; t1 += e1v * w1[k];
      }
      acc0 += fmaxf(p0, 0.f) + fmaxf(t0, 0.f);
      acc1 += fmaxf(p1, 0.f) + fmaxf(t1, 0.f);
    }
    if (j < cnt) {
      int s0 = __builtin_amdgcn_readfirstlane(__shfl(v.x, j));
      int r0 = __builtin_amdgcn_readfirstlane(__shfl(v.y, j));
      u32 q0 = *(const u32*)(q + (size_t)s0 * 128 + 2 * lane);
      const float* er0 = ea + (size_t)r0 * 16;
      float p0 = pb0 + bflo(q0), p1 = pb1 + bfhi(q0);
#pragma unroll
      for (int k = 0; k < 16; ++k) { float ev = er0[k]; p0 += ev * w0[k]; p1 += ev * w1[k]; }
      acc0 += fmaxf(p0, 0.f);
      acc1 += fmaxf(p1, 0.f);
    }
  }
  u32 outv = ((u32)f2b(acc0)) | (((u32)f2b(acc1)) << 16);
  *(u32*)(Hsum + (size_t)node * 128 + 2 * lane) = outv;
}

extern "C" void kernel_launch(void* const* d_in, const int* in_sizes, int n_in,
                              void* d_out, int out_size, void* d_ws, size_t ws_size,
                              hipStream_t stream) {
  const float* x      = (const float*)d_in[0];
  const float* mask   = (const float*)d_in[1];
  const float* ea     = (const float*)d_in[2];
  const int*   eidx   = (const int*)d_in[3];
  const float* m_w1   = (const float*)d_in[4];
  const float* m_b1   = (const float*)d_in[5];
  const float* m_w2   = (const float*)d_in[6];
  const float* m_b2   = (const float*)d_in[7];
  const float* ea0_w1 = (const float*)d_in[8];
  const float* ea0_b1 = (const float*)d_in[9];
  const float* ea0_w2 = (const float*)d_in[10];
  const float* ea0_b2 = (const float*)d_in[11];
  const float* tag0_w = (const float*)d_in[12];
  const float* tag0_b = (const float*)d_in[13];
  const float* ea1_w1 = (const float*)d_in[14];
  const float* ea1_b1 = (const float*)d_in[15];
  const float* ea1_w2 = (const float*)d_in[16];
  const float* ea1_b2 = (const float*)d_in[17];
  const float* tag1_w = (const float*)d_in[18];
  const float* tag1_b = (const float*)d_in[19];
  const float* ea2_w1 = (const float*)d_in[20];
  const float* ea2_b1 = (const float*)d_in[21];
  const float* ea2_w2 = (const float*)d_in[22];
  const float* ea2_b2 = (const float*)d_in[23];

  const int N = in_sizes[0] / 16;   // 20000
  const int E = in_sizes[2] / 16;   // 160000
  const int E2 = 2 * E;

  char* w = (char*)d_ws;
  auto alloc = [&](size_t bytes) { char* p = w; w += (bytes + 255) & ~(size_t)255; return p; };
  int*   degi   = (int*)alloc((size_t)N * 4);
  int*   cursor = (int*)alloc((size_t)N * 4);
  int*   rowptr = (int*)alloc((size_t)(N + 1) * 4);
  float* dis    = (float*)alloc((size_t)N * 4);
  int2*  cw     = (int2*)alloc((size_t)E2 * 8);
  int2*  ce     = (int2*)alloc((size_t)E2 * 8);
  float* h16    = (float*)alloc((size_t)N * 16 * 4);
  float* Hf     = (float*)alloc((size_t)N * 128 * 4);
  u16*   X0     = (u16*)alloc((size_t)N * 128 * 2);
  u16*   X1     = (u16*)alloc((size_t)N * 128 * 2);
  u16*   X2     = (u16*)alloc((size_t)N * 128 * 2);
  u16*   Wt     = (u16*)alloc((size_t)14 * 16384 * 2);
  (void)ws_size; (void)n_in; (void)out_size;

  hipMemsetAsync(degi, 0, (size_t)N * 4, stream);
  hipMemsetAsync(cursor, 0, (size_t)N * 4, stream);
  prep_wt<<<112, 256, 0, stream>>>(ea0_w2, tag0_w, ea1_w1, ea1_w2, tag1_w, ea2_w1, Wt);
  count_deg<<<(E + 255) / 256, 256, 0, stream>>>(eidx, degi, E);
  csr_scan<<<1, 1024, 0, stream>>>(degi, rowptr, dis, N);
  fill_csr<<<(E2 + 255) / 256, 256, 0, stream>>>(eidx, rowptr, cursor, dis, cw, ce, E);

  const int gb = (N + 7) / 8;          // VALU gemm blocks
  const int gm = (N + 63) / 64;        // MFMA gemm blocks
  const int g4 = (N + 3) / 4;          // gather blocks (4 waves = 4 nodes)
  u16* WT_ea0w2  = Wt + 0 * 16384;
  u16* WT_tag0   = Wt + 1 * 16384;
  u16* WT_ea1d   = Wt + 5 * 16384;
  u16* WT_ea1s   = Wt + 6 * 16384;
  u16* WT_ea1w2  = Wt + 7 * 16384;
  u16* WT_tag1   = Wt + 8 * 16384;
  u16* WT_ea2d   = Wt + 12 * 16384;
  u16* WT_ea2s   = Wt + 13 * 16384;

  // ---- mask MLP + residual ----
  gemm_node<16, 128, false, false><<<gb, 128, 0, stream>>>(mask, m_w1, Hf, m_b1, nullptr, nullptr, N, 1);
  gemm_node<128, 16, false, false><<<gb, 128, 0, stream>>>(Hf, m_w2, h16, m_b2, nullptr, x, N, 0);

  // ---- EA0 ----
  gemm_node<16, 128, false, true><<<gb, 128, 0, stream>>>(h16, ea0_w1, X0, ea0_b1, nullptr, nullptr, N, 0);
  gemm_node<16, 128, false, true><<<gb, 128, 0, stream>>>(h16, ea0_w1 + 16 * 128, X1, nullptr, nullptr, nullptr, N, 0);
  ea_gather3<<<g4, 256, 0, stream>>>(X0, X1, ea0_w1 + 32 * 128, ea, rowptr, ce, X2, N);
  gemm_mfma<true><<<gm, 256, 0, stream>>>(X2, WT_ea0w2, X0, nullptr, ea0_b2, degi, N, 1);   // h1 -> X0

  // ---- TAG0 ----
  gemm_mfma<false><<<gm, 256, 0, stream>>>(X0, WT_tag0, Hf, nullptr, nullptr, nullptr, N, 0);
  tag_gather3<<<g4, 256, 0, stream>>>(X0, dis, rowptr, cw, X1, N);
  gemm_mfma<false><<<gm, 256, 0, stream>>>(X1, WT_tag0 + 16384, Hf, Hf, nullptr, nullptr, N, 0);
  tag_gather3<<<g4, 256, 0, stream>>>(X1, dis, rowptr, cw, X2, N);
  gemm_mfma<false><<<gm, 256, 0, stream>>>(X2, WT_tag0 + 2 * 16384, Hf, Hf, nullptr, nullptr, N, 0);
  tag_gather3<<<g4, 256, 0, stream>>>(X2, dis, rowptr, cw, X1, N);
  gemm_mfma<true><<<gm, 256, 0, stream>>>(X1, WT_tag0 + 3 * 16384, X0, Hf, tag0_b, nullptr, N, 1);  // h2 -> X0

  // ---- EA1 ----
  gemm_mfma_dual<<<gm, 256, 0, stream>>>(X0, WT_ea1d, WT_ea1s, X1, X2, ea1_b1, N);          // pb->X1, q->X2
  ea_gather3<<<g4, 256, 0, stream>>>(X1, X2, ea1_w1 + 256 * 128, ea, rowptr, ce, X0, N);
  gemm_mfma<true><<<gm, 256, 0, stream>>>(X0, WT_ea1w2, X1, nullptr, ea1_b2, degi, N, 1);   // h3 -> X1

  // ---- TAG1 ----
  gemm_mfma<false><<<gm, 256, 0, stream>>>(X1, WT_tag1, Hf, nullptr, nullptr, nullptr, N, 0);
  tag_gather3<<<g4, 256, 0, stream>>>(X1, dis, rowptr, cw, X0, N);
  gemm_mfma<false><<<gm, 256, 0, stream>>>(X0, WT_tag1 + 16384, Hf, Hf, nullptr, nullptr, N, 0);
  tag_gather3<<<g4, 256, 0, stream>>>(X0, dis, rowptr, cw, X2, N);
  gemm_mfma<false><<<gm, 256, 0, stream>>>(X2, WT_tag1 + 2 * 16384, Hf, Hf, nullptr, nullptr, N, 0);
  tag_gather3<<<g4, 256, 0, stream>>>(X2, dis, rowptr, cw, X0, N);
  gemm_mfma<true><<<gm, 256, 0, stream>>>(X0, WT_tag1 + 3 * 16384, X1, Hf, tag1_b, nullptr, N, 1);  // h4 -> X1

  // ---- EA2 ----
  gemm_mfma_dual<<<gm, 256, 0, stream>>>(X1, WT_ea2d, WT_ea2s, X0, X2, ea2_b1, N);          // pb->X0, q->X2
  ea_gather3<<<g4, 256, 0, stream>>>(X0, X2, ea2_w1 + 256 * 128, ea, rowptr, ce, X1, N);
  gemm_node<128, 16, true, false><<<gb, 128, 0, stream>>>(X1, ea2_w2, (float*)d_out, ea2_b2, degi, nullptr, N, 0);
}

// Round 6
// 538.403 us; speedup vs baseline: 1.7605x; 1.1048x over previous
//
#include <hip/hip_runtime.h>

typedef unsigned short u16;
typedef unsigned int u32;

using bfrag = __attribute__((ext_vector_type(8))) short;   // 8 bf16 (4 VGPRs)
using f32x4 = __attribute__((ext_vector_type(4))) float;   // 4 fp32 acc

// ---------- bf16 / f16 helpers ----------
__device__ __forceinline__ float b2f(u16 u) {
  union { u32 i; float f; } c; c.i = ((u32)u) << 16; return c.f;
}
__device__ __forceinline__ float bflo(u32 u) { union { u32 i; float f; } c; c.i = u << 16; return c.f; }
__device__ __forceinline__ float bfhi(u32 u) { union { u32 i; float f; } c; c.i = u & 0xffff0000u; return c.f; }
__device__ __forceinline__ u16 f2b(float f) {  // round-to-nearest-even
  union { float f; u32 i; } c; c.f = f;
  u32 x = c.i;
  u32 r = x + 0x7fffu + ((x >> 16) & 1u);
  return (u16)(r >> 16);
}
__device__ __forceinline__ u32 packb2(float x, float y) {
  return ((u32)f2b(x)) | (((u32)f2b(y)) << 16);
}
__device__ __forceinline__ u32 packh2(float x, float y) {
  union { _Float16 h[2]; u32 u; } c; c.h[0] = (_Float16)x; c.h[1] = (_Float16)y; return c.u;
}
__device__ __forceinline__ float h2lo(u32 u) { union { u32 i; _Float16 h[2]; } c; c.i = u; return (float)c.h[0]; }
__device__ __forceinline__ float h2hi(u32 u) { union { u32 i; _Float16 h[2]; } c; c.i = u; return (float)c.h[1]; }
__device__ __forceinline__ int rfl(int v) { return __builtin_amdgcn_readfirstlane(v); }

// ---------- CSR build ----------
__global__ __launch_bounds__(256) void count_deg(const int* __restrict__ eidx,
                                                 int* __restrict__ degi, int E) {
  int e = blockIdx.x * 256 + threadIdx.x;
  if (e >= E) return;
  atomicAdd(&degi[eidx[E + e]], 1);
  atomicAdd(&degi[eidx[e]], 1);
}

__global__ __launch_bounds__(1024) void csr_scan(const int* __restrict__ degi,
                                                 int* __restrict__ rowptr,
                                                 float* __restrict__ dis, int n) {
  __shared__ int sums[1024];
  int tid = threadIdx.x;
  const int CH = (n + 1023) / 1024;
  int base = tid * CH;
  int s = 0;
  for (int i = 0; i < CH; ++i) { int j = base + i; if (j < n) s += degi[j]; }
  sums[tid] = s;
  __syncthreads();
  for (int off = 1; off < 1024; off <<= 1) {
    int v = sums[tid];
    int add = (tid >= off) ? sums[tid - off] : 0;
    __syncthreads();
    sums[tid] = v + add;
    __syncthreads();
  }
  int run = sums[tid] - s;
  for (int i = 0; i < CH; ++i) {
    int j = base + i;
    if (j < n) { rowptr[j] = run; run += degi[j]; }
  }
  if (tid == 1023) rowptr[n] = sums[1023];
  for (int j = tid; j < n; j += 1024) {
    int d = degi[j];
    dis[j] = d > 0 ? rsqrtf((float)d) : 0.0f;
  }
}

// cw[pos] = (src, bits(dis[src])); ce[pos] = (src, edge_id)
__global__ __launch_bounds__(256) void fill_csr(const int* __restrict__ eidx,
                                                const int* __restrict__ rowptr,
                                                int* __restrict__ cursor,
                                                const float* __restrict__ dis,
                                                int2* __restrict__ cw,
                                                int2* __restrict__ ce, int E) {
  int i = blockIdx.x * 256 + threadIdx.x;
  int E2 = 2 * E;
  if (i >= E2) return;
  int e = (i < E) ? i : i - E;
  int s, d;
  if (i < E) { s = eidx[e]; d = eidx[E + e]; }
  else       { s = eidx[E + e]; d = eidx[e]; }
  int pos = rowptr[d] + atomicAdd(&cursor[d], 1);
  cw[pos] = make_int2(s, __float_as_int(dis[s]));
  ce[pos] = make_int2(s, e);
}

// ---------- weight prep: fp32 [128k][128n] -> bf16 [128n][128k] ----------
__global__ __launch_bounds__(256) void prep_wt(
    const float* __restrict__ ea0_w2, const float* __restrict__ tag0_w,
    const float* __restrict__ ea1_w1, const float* __restrict__ ea1_w2,
    const float* __restrict__ tag1_w, const float* __restrict__ ea2_w1,
    u16* __restrict__ Wt) {
  int mat = blockIdx.x >> 3, chunk = blockIdx.x & 7;
  const float* src;
  if      (mat == 0)  src = ea0_w2;
  else if (mat <= 4)  src = tag0_w + (mat - 1) * 16384;
  else if (mat == 5)  src = ea1_w1;
  else if (mat == 6)  src = ea1_w1 + 16384;
  else if (mat == 7)  src = ea1_w2;
  else if (mat <= 11) src = tag1_w + (mat - 8) * 16384;
  else if (mat == 12) src = ea2_w1;
  else                src = ea2_w1 + 16384;
  u16* dst = Wt + mat * 16384;
  int t = threadIdx.x;
  for (int i = 0; i < 8; ++i) {
    int idx = chunk * 2048 + i * 256 + t;
    int k = idx >> 7, n = idx & 127;
    dst[n * 128 + k] = f2b(src[idx]);
  }
}

// ---------- edge projection tables: P_l[e] = ea[e] @ W1ea_l  (f16, all 3 layers) ----------
__global__ __launch_bounds__(256) void ea_proj(
    const float* __restrict__ ea, const float* __restrict__ wA,
    const float* __restrict__ wB, const float* __restrict__ wC,
    u16* __restrict__ P0, u16* __restrict__ P1, u16* __restrict__ P2, int E) {
  int lane = threadIdx.x & 63;
  int wid = rfl(blockIdx.x * 4 + (threadIdx.x >> 6));
  int nw = gridDim.x * 4;
  float a0[16], a1[16], b0[16], b1[16], c0[16], c1[16];
#pragma unroll
  for (int k = 0; k < 16; ++k) {
    float2 va = *(const float2*)(wA + k * 128 + 2 * lane);
    float2 vb = *(const float2*)(wB + k * 128 + 2 * lane);
    float2 vc = *(const float2*)(wC + k * 128 + 2 * lane);
    a0[k] = va.x; a1[k] = va.y;
    b0[k] = vb.x; b1[k] = vb.y;
    c0[k] = vc.x; c1[k] = vc.y;
  }
  for (int e = wid; e < E; e += nw) {
    const float* er = ea + (size_t)e * 16;
    float s0 = 0, s1 = 0, t0 = 0, t1 = 0, u0 = 0, u1 = 0;
#pragma unroll
    for (int k = 0; k < 16; ++k) {
      float ev = er[k];
      s0 += ev * a0[k]; s1 += ev * a1[k];
      t0 += ev * b0[k]; t1 += ev * b1[k];
      u0 += ev * c0[k]; u1 += ev * c1[k];
    }
    size_t off = (size_t)e * 128 + 2 * lane;
    *(u32*)(P0 + off) = packh2(s0, s1);
    *(u32*)(P1 + off) = packh2(t0, t1);
    *(u32*)(P2 + off) = packh2(u0, u1);
  }
}

// ---------- MFMA GEMM: C[M,128] = A[M,128]bf16 @ W (+bias/deg*bias +relu) ----------
template<bool OUTBF16>
__global__ __launch_bounds__(256) void gemm_mfma(
    const u16* __restrict__ A, const u16* __restrict__ Wt,
    void* __restrict__ Cout, const float* __restrict__ bias,
    const int* __restrict__ degi, int M, int relu) {
  __shared__ u16 Alds[64 * 136];
  __shared__ u16 Wlds[128 * 136];
  int t = threadIdx.x;
  int base = blockIdx.x * 64;
#pragma unroll
  for (int i = 0; i < 8; ++i) {
    int idx = (i * 256 + t) * 8;
    int n = idx >> 7, k = idx & 127;
    uint4 v = *(const uint4*)(Wt + idx);
    *(uint4*)(Wlds + n * 136 + k) = v;
  }
#pragma unroll
  for (int i = 0; i < 4; ++i) {
    int idx = (i * 256 + t) * 8;
    int r = idx >> 7, k = idx & 127;
    int row = base + r;
    uint4 v = make_uint4(0, 0, 0, 0);
    if (row < M) v = *(const uint4*)(A + (size_t)row * 128 + k);
    *(uint4*)(Alds + r * 136 + k) = v;
  }
  __syncthreads();
  int wave = t >> 6, lane = t & 63;
  int m = lane & 15, quad = lane >> 4;
  int arow = wave * 16 + m;
  bfrag a[4];
#pragma unroll
  for (int ks = 0; ks < 4; ++ks)
    a[ks] = *(const bfrag*)(Alds + arow * 136 + ks * 32 + quad * 8);
  f32x4 acc[8];
#pragma unroll
  for (int nt = 0; nt < 8; ++nt) acc[nt] = (f32x4){0.f, 0.f, 0.f, 0.f};
#pragma unroll
  for (int nt = 0; nt < 8; ++nt) {
    int n = nt * 16 + m;
#pragma unroll
    for (int ks = 0; ks < 4; ++ks) {
      bfrag b = *(const bfrag*)(Wlds + n * 136 + ks * 32 + quad * 8);
      acc[nt] = __builtin_amdgcn_mfma_f32_16x16x32_bf16(a[ks], b, acc[nt], 0, 0, 0);
    }
  }
#pragma unroll
  for (int nt = 0; nt < 8; ++nt) {
    int col = nt * 16 + m;
#pragma unroll
    for (int r = 0; r < 4; ++r) {
      int row = base + wave * 16 + quad * 4 + r;
      if (row < M) {
        float v = acc[nt][r];
        if (bias) { float b = bias[col]; v += degi ? b * (float)degi[row] : b; }
        if (relu) v = fmaxf(v, 0.f);
        if (OUTBF16) ((u16*)Cout)[(size_t)row * 128 + col] = f2b(v);
        else         ((float*)Cout)[(size_t)row * 128 + col] = v;
      }
    }
  }
}

// ---------- dual MFMA GEMM: C0 = A@W0 (+bias0), C1 = A@W1 (both bf16) ----------
__global__ __launch_bounds__(256) void gemm_mfma_dual(
    const u16* __restrict__ A, const u16* __restrict__ W0t, const u16* __restrict__ W1t,
    u16* __restrict__ C0, u16* __restrict__ C1, const float* __restrict__ bias0, int M) {
  __shared__ u16 Alds[64 * 136];
  __shared__ u16 Wlds[128 * 136];
  int t = threadIdx.x;
  int base = blockIdx.x * 64;
#pragma unroll
  for (int i = 0; i < 8; ++i) {
    int idx = (i * 256 + t) * 8;
    int n = idx >> 7, k = idx & 127;
    uint4 v = *(const uint4*)(W0t + idx);
    *(uint4*)(Wlds + n * 136 + k) = v;
  }
#pragma unroll
  for (int i = 0; i < 4; ++i) {
    int idx = (i * 256 + t) * 8;
    int r = idx >> 7, k = idx & 127;
    int row = base + r;
    uint4 v = make_uint4(0, 0, 0, 0);
    if (row < M) v = *(const uint4*)(A + (size_t)row * 128 + k);
    *(uint4*)(Alds + r * 136 + k) = v;
  }
  __syncthreads();
  int wave = t >> 6, lane = t & 63;
  int m = lane & 15, quad = lane >> 4;
  int arow = wave * 16 + m;
  bfrag a[4];
#pragma unroll
  for (int ks = 0; ks < 4; ++ks)
    a[ks] = *(const bfrag*)(Alds + arow * 136 + ks * 32 + quad * 8);
  f32x4 acc0[8], acc1[8];
#pragma unroll
  for (int nt = 0; nt < 8; ++nt) { acc0[nt] = (f32x4){0,0,0,0}; acc1[nt] = (f32x4){0,0,0,0}; }
#pragma unroll
  for (int nt = 0; nt < 8; ++nt) {
    int n = nt * 16 + m;
#pragma unroll
    for (int ks = 0; ks < 4; ++ks) {
      bfrag b = *(const bfrag*)(Wlds + n * 136 + ks * 32 + quad * 8);
      acc0[nt] = __builtin_amdgcn_mfma_f32_16x16x32_bf16(a[ks], b, acc0[nt], 0, 0, 0);
    }
  }
  __syncthreads();
#pragma unroll
  for (int i = 0; i < 8; ++i) {
    int idx = (i * 256 + t) * 8;
    int n = idx >> 7, k = idx & 127;
    uint4 v = *(const uint4*)(W1t + idx);
    *(uint4*)(Wlds + n * 136 + k) = v;
  }
  __syncthreads();
#pragma unroll
  for (int nt = 0; nt < 8; ++nt) {
    int n = nt * 16 + m;
#pragma unroll
    for (int ks = 0; ks < 4; ++ks) {
      bfrag b = *(const bfrag*)(Wlds + n * 136 + ks * 32 + quad * 8);
      acc1[nt] = __builtin_amdgcn_mfma_f32_16x16x32_bf16(a[ks], b, acc1[nt], 0, 0, 0);
    }
  }
#pragma unroll
  for (int nt = 0; nt < 8; ++nt) {
    int col = nt * 16 + m;
#pragma unroll
    for (int r = 0; r < 4; ++r) {
      int row = base + wave * 16 + quad * 4 + r;
      if (row < M) {
        float v0 = acc0[nt][r];
        if (bias0) v0 += bias0[col];
        C0[(size_t)row * 128 + col] = f2b(v0);
        C1[(size_t)row * 128 + col] = f2b(acc1[nt][r]);
      }
    }
  }
}

// ---------- VALU GEMM (small K or small KO) ----------
template<int KI, int KO, bool ABF16, bool OUTBF16>
__global__ __launch_bounds__(128) void gemm_node(
    const void* __restrict__ A_, const float* __restrict__ W, void* __restrict__ Cout,
    const float* __restrict__ bias, const int* __restrict__ degi,
    const float* __restrict__ resid, int M, int relu) {
  const int ROWS = 8;
  int t = threadIdx.x;
  int base = blockIdx.x * ROWS;
  __shared__ float Al[ROWS * KI];
  for (int i = t; i < ROWS * KI; i += 128) {
    int r = i / KI, k = i - r * KI;
    int row = base + r;
    float v = 0.f;
    if (row < M) {
      if (ABF16) v = b2f(((const u16*)A_)[(size_t)row * KI + k]);
      else       v = ((const float*)A_)[(size_t)row * KI + k];
    }
    Al[i] = v;
  }
  __syncthreads();
  if (KO == 128) {
    float acc[ROWS];
#pragma unroll
    for (int r = 0; r < ROWS; ++r) acc[r] = 0.f;
    for (int k = 0; k < KI; ++k) {
      float w = W[k * 128 + t];
#pragma unroll
      for (int r = 0; r < ROWS; ++r) acc[r] += Al[r * KI + k] * w;
    }
#pragma unroll
    for (int r = 0; r < ROWS; ++r) {
      int row = base + r;
      if (row >= M) break;
      float v = acc[r];
      if (bias)  { float b = bias[t]; v += degi ? b * (float)degi[row] : b; }
      if (resid) v += resid[(size_t)row * 128 + t];
      if (relu)  v = fmaxf(v, 0.f);
      if (OUTBF16) ((u16*)Cout)[(size_t)row * 128 + t] = f2b(v);
      else         ((float*)Cout)[(size_t)row * 128 + t] = v;
    }
  } else {
    int r = t >> 4, u = t & 15;
    int row = base + r;
    float acc = 0.f;
    for (int k = 0; k < KI; ++k) acc += Al[r * KI + k] * W[k * 16 + u];
    if (row < M) {
      float v = acc;
      if (bias)  { float b = bias[u]; v += degi ? b * (float)degi[row] : b; }
      if (resid) v += resid[(size_t)row * 16 + u];
      if (relu)  v = fmaxf(v, 0.f);
      if (OUTBF16) ((u16*)Cout)[(size_t)row * 16 + u] = f2b(v);
      else         ((float*)Cout)[(size_t)row * 16 + u] = v;
    }
  }
}

// ---------- TAG gather v4: scalar records, saddr row loads, fused Cin (+bias+relu) ----------
// out[n] = Cin[n] + dis[n] * sum_e w_e * g[src_e]   ( +bias, relu if FINAL )
template<bool FINAL>
__global__ __launch_bounds__(256) void tag_gather4(
    const u16* __restrict__ g, const u16* __restrict__ Cin,
    const float* __restrict__ bias, const float* __restrict__ dis,
    const int* __restrict__ rowptr, const int2* __restrict__ cw,
    u16* __restrict__ out, int N) {
  int wave = threadIdx.x >> 6, lane = threadIdx.x & 63;
  int node = blockIdx.x * 4 + wave;
  if (node >= N) return;
  int e0 = rfl(rowptr[node]);
  int e1 = rfl(rowptr[node + 1]);
  float a0 = 0, a1 = 0, b0 = 0, b1 = 0;
  int e = e0;
  for (; e + 4 <= e1; e += 4) {
    int4 r01 = *(const int4*)(cw + e);
    int4 r23 = *(const int4*)(cw + e + 2);
    int s0 = rfl(r01.x); float w0 = __uint_as_float(rfl(r01.y));
    int s1 = rfl(r01.z); float w1 = __uint_as_float(rfl(r01.w));
    int s2 = rfl(r23.x); float w2 = __uint_as_float(rfl(r23.y));
    int s3 = rfl(r23.z); float w3 = __uint_as_float(rfl(r23.w));
    u32 h0 = *((const u32*)(g + (size_t)s0 * 128) + lane);
    u32 h1 = *((const u32*)(g + (size_t)s1 * 128) + lane);
    u32 h2 = *((const u32*)(g + (size_t)s2 * 128) + lane);
    u32 h3 = *((const u32*)(g + (size_t)s3 * 128) + lane);
    a0 += w0 * bflo(h0); a1 += w0 * bfhi(h0);
    b0 += w1 * bflo(h1); b1 += w1 * bfhi(h1);
    a0 += w2 * bflo(h2); a1 += w2 * bfhi(h2);
    b0 += w3 * bflo(h3); b1 += w3 * bfhi(h3);
  }
  for (; e < e1; ++e) {
    int2 r = cw[e];
    int s0 = rfl(r.x); float w0 = __uint_as_float(rfl(r.y));
    u32 h0 = *((const u32*)(g + (size_t)s0 * 128) + lane);
    a0 += w0 * bflo(h0); a1 += w0 * bfhi(h0);
  }
  float dn = dis[node];
  float r0v = dn * (a0 + b0), r1v = dn * (a1 + b1);
  u32 cin = *((const u32*)(Cin + (size_t)node * 128) + lane);
  r0v += bflo(cin); r1v += bfhi(cin);
  if (FINAL) {
    float2 bv = *(const float2*)(bias + 2 * lane);
    r0v = fmaxf(r0v + bv.x, 0.f);
    r1v = fmaxf(r1v + bv.y, 0.f);
  }
  *((u32*)(out + (size_t)node * 128) + lane) = packb2(r0v, r1v);
}

// ---------- EA gather v4: Hsum[n] = sum_e relu(pb[n] + q[src] + P[edge]) ----------
__global__ __launch_bounds__(256) void ea_gather4(
    const u16* __restrict__ pb, const u16* __restrict__ q,
    const u16* __restrict__ P /*f16 [E,128]*/,
    const int* __restrict__ rowptr, const int2* __restrict__ ce,
    u16* __restrict__ Hsum, int N) {
  int wave = threadIdx.x >> 6, lane = threadIdx.x & 63;
  int node = blockIdx.x * 4 + wave;
  if (node >= N) return;
  int e0 = rfl(rowptr[node]);
  int e1 = rfl(rowptr[node + 1]);
  u32 pbu = *((const u32*)(pb + (size_t)node * 128) + lane);
  float pb0 = bflo(pbu), pb1 = bfhi(pbu);
  float acc0 = 0, acc1 = 0;
  int e = e0;
  for (; e + 2 <= e1; e += 2) {
    int4 r01 = *(const int4*)(ce + e);
    int s0 = rfl(r01.x), p0i = rfl(r01.y);
    int s1 = rfl(r01.z), p1i = rfl(r01.w);
    u32 q0 = *((const u32*)(q + (size_t)s0 * 128) + lane);
    u32 v0 = *((const u32*)(P + (size_t)p0i * 128) + lane);
    u32 q1 = *((const u32*)(q + (size_t)s1 * 128) + lane);
    u32 v1 = *((const u32*)(P + (size_t)p1i * 128) + lane);
    float m0 = pb0 + bflo(q0) + h2lo(v0);
    float m1 = pb1 + bfhi(q0) + h2hi(v0);
    float n0 = pb0 + bflo(q1) + h2lo(v1);
    float n1 = pb1 + bfhi(q1) + h2hi(v1);
    acc0 += fmaxf(m0, 0.f) + fmaxf(n0, 0.f);
    acc1 += fmaxf(m1, 0.f) + fmaxf(n1, 0.f);
  }
  if (e < e1) {
    int2 r = ce[e];
    int s0 = rfl(r.x), p0i = rfl(r.y);
    u32 q0 = *((const u32*)(q + (size_t)s0 * 128) + lane);
    u32 v0 = *((const u32*)(P + (size_t)p0i * 128) + lane);
    acc0 += fmaxf(pb0 + bflo(q0) + h2lo(v0), 0.f);
    acc1 += fmaxf(pb1 + bfhi(q0) + h2hi(v0), 0.f);
  }
  *((u32*)(Hsum + (size_t)node * 128) + lane) = packb2(acc0, acc1);
}

extern "C" void kernel_launch(void* const* d_in, const int* in_sizes, int n_in,
                              void* d_out, int out_size, void* d_ws, size_t ws_size,
                              hipStream_t stream) {
  const float* x      = (const float*)d_in[0];
  const float* mask   = (const float*)d_in[1];
  const float* ea     = (const float*)d_in[2];
  const int*   eidx   = (const int*)d_in[3];
  const float* m_w1   = (const float*)d_in[4];
  const float* m_b1   = (const float*)d_in[5];
  const float* m_w2   = (const float*)d_in[6];
  const float* m_b2   = (const float*)d_in[7];
  const float* ea0_w1 = (const float*)d_in[8];
  const float* ea0_b1 = (const float*)d_in[9];
  const float* ea0_w2 = (const float*)d_in[10];
  const float* ea0_b2 = (const float*)d_in[11];
  const float* tag0_w = (const float*)d_in[12];
  const float* tag0_b = (const float*)d_in[13];
  const float* ea1_w1 = (const float*)d_in[14];
  const float* ea1_b1 = (const float*)d_in[15];
  const float* ea1_w2 = (const float*)d_in[16];
  const float* ea1_b2 = (const float*)d_in[17];
  const float* tag1_w = (const float*)d_in[18];
  const float* tag1_b = (const float*)d_in[19];
  const float* ea2_w1 = (const float*)d_in[20];
  const float* ea2_b1 = (const float*)d_in[21];
  const float* ea2_w2 = (const float*)d_in[22];
  const float* ea2_b2 = (const float*)d_in[23];

  const int N = in_sizes[0] / 16;   // 20000
  const int E = in_sizes[2] / 16;   // 160000
  const int E2 = 2 * E;

  char* w = (char*)d_ws;
  auto alloc = [&](size_t bytes) { char* p = w; w += (bytes + 255) & ~(size_t)255; return p; };
  int*   degi   = (int*)alloc((size_t)N * 4);
  int*   cursor = (int*)alloc((size_t)N * 4);
  int*   rowptr = (int*)alloc((size_t)(N + 1) * 4);
  float* dis    = (float*)alloc((size_t)N * 4);
  int2*  cw     = (int2*)alloc((size_t)E2 * 8);
  int2*  ce     = (int2*)alloc((size_t)E2 * 8);
  float* Hf     = (float*)alloc((size_t)N * 128 * 4);
  float* h16    = (float*)alloc((size_t)N * 16 * 4);
  u16*   X0     = (u16*)alloc((size_t)N * 128 * 2);
  u16*   X1     = (u16*)alloc((size_t)N * 128 * 2);
  u16*   X2     = (u16*)alloc((size_t)N * 128 * 2);
  u16*   G0     = (u16*)alloc((size_t)N * 128 * 2);
  u16*   G1     = (u16*)alloc((size_t)N * 128 * 2);
  u16*   G2     = (u16*)alloc((size_t)N * 128 * 2);
  u16*   G3     = (u16*)alloc((size_t)N * 128 * 2);
  u16*   Wt     = (u16*)alloc((size_t)14 * 16384 * 2);
  u16*   P0     = (u16*)alloc((size_t)E * 128 * 2);   // f16 tables
  u16*   P1     = (u16*)alloc((size_t)E * 128 * 2);
  u16*   P2     = (u16*)alloc((size_t)E * 128 * 2);
  (void)ws_size; (void)n_in; (void)out_size;

  hipMemsetAsync(degi, 0, (size_t)N * 4, stream);
  hipMemsetAsync(cursor, 0, (size_t)N * 4, stream);
  prep_wt<<<112, 256, 0, stream>>>(ea0_w2, tag0_w, ea1_w1, ea1_w2, tag1_w, ea2_w1, Wt);
  ea_proj<<<640, 256, 0, stream>>>(ea, ea0_w1 + 32 * 128, ea1_w1 + 256 * 128,
                                   ea2_w1 + 256 * 128, P0, P1, P2, E);
  count_deg<<<(E + 255) / 256, 256, 0, stream>>>(eidx, degi, E);
  csr_scan<<<1, 1024, 0, stream>>>(degi, rowptr, dis, N);
  fill_csr<<<(E2 + 255) / 256, 256, 0, stream>>>(eidx, rowptr, cursor, dis, cw, ce, E);

  const int gb = (N + 7) / 8;
  const int gm = (N + 63) / 64;
  const int g4 = (N + 3) / 4;
  u16* WT_ea0w2  = Wt + 0 * 16384;
  u16* WT_tag0   = Wt + 1 * 16384;
  u16* WT_ea1d   = Wt + 5 * 16384;
  u16* WT_ea1s   = Wt + 6 * 16384;
  u16* WT_ea1w2  = Wt + 7 * 16384;
  u16* WT_tag1   = Wt + 8 * 16384;
  u16* WT_ea2d   = Wt + 12 * 16384;
  u16* WT_ea2s   = Wt + 13 * 16384;

  // ---- mask MLP + residual: h16 = relu(mask@m_w1+b1)@m_w2 + b2 + x ----
  gemm_node<16, 128, false, false><<<gb, 128, 0, stream>>>(mask, m_w1, Hf, m_b1, nullptr, nullptr, N, 1);
  gemm_node<128, 16, false, false><<<gb, 128, 0, stream>>>(Hf, m_w2, h16, m_b2, nullptr, x, N, 0);

  // ---- EA0 ----
  gemm_node<16, 128, false, true><<<gb, 128, 0, stream>>>(h16, ea0_w1, X0, ea0_b1, nullptr, nullptr, N, 0);
  gemm_node<16, 128, false, true><<<gb, 128, 0, stream>>>(h16, ea0_w1 + 16 * 128, X1, nullptr, nullptr, nullptr, N, 0);
  ea_gather4<<<g4, 256, 0, stream>>>(X0, X1, P0, rowptr, ce, X2, N);
  gemm_mfma<true><<<gm, 256, 0, stream>>>(X2, WT_ea0w2, X0, ea0_b2, degi, N, 1);   // h1 -> X0

  // ---- TAG0: g_k = h1@lin_k; h2 = relu(g0 + L(g1 + L(g2 + L g3)) + b) ----
  gemm_mfma_dual<<<gm, 256, 0, stream>>>(X0, WT_tag0, WT_tag0 + 16384, G0, G1, nullptr, N);
  gemm_mfma_dual<<<gm, 256, 0, stream>>>(X0, WT_tag0 + 2 * 16384, WT_tag0 + 3 * 16384, G2, G3, nullptr, N);
  tag_gather4<false><<<g4, 256, 0, stream>>>(G3, G2, nullptr, dis, rowptr, cw, X1, N);
  tag_gather4<false><<<g4, 256, 0, stream>>>(X1, G1, nullptr, dis, rowptr, cw, X2, N);
  tag_gather4<true><<<g4, 256, 0, stream>>>(X2, G0, tag0_b, dis, rowptr, cw, X0, N);  // h2 -> X0

  // ---- EA1 ----
  gemm_mfma_dual<<<gm, 256, 0, stream>>>(X0, WT_ea1d, WT_ea1s, X1, X2, ea1_b1, N);
  ea_gather4<<<g4, 256, 0, stream>>>(X1, X2, P1, rowptr, ce, G0, N);
  gemm_mfma<true><<<gm, 256, 0, stream>>>(G0, WT_ea1w2, X0, ea1_b2, degi, N, 1);   // h3 -> X0

  // ---- TAG1 ----
  gemm_mfma_dual<<<gm, 256, 0, stream>>>(X0, WT_tag1, WT_tag1 + 16384, G0, G1, nullptr, N);
  gemm_mfma_dual<<<gm, 256, 0, stream>>>(X0, WT_tag1 + 2 * 16384, WT_tag1 + 3 * 16384, G2, G3, nullptr, N);
  tag_gather4<false><<<g4, 256, 0, stream>>>(G3, G2, nullptr, dis, rowptr, cw, X1, N);
  tag_gather4<false><<<g4, 256, 0, stream>>>(X1, G1, nullptr, dis, rowptr, cw, X2, N);
  tag_gather4<true><<<g4, 256, 0, stream>>>(X2, G0, tag1_b, dis, rowptr, cw, X0, N);  // h4 -> X0

  // ---- EA2 (final, out 16, fp32) ----
  gemm_mfma_dual<<<gm, 256, 0, stream>>>(X0, WT_ea2d, WT_ea2s, X1, X2, ea2_b1, N);
  ea_gather4<<<g4, 256, 0, stream>>>(X1, X2, P2, rowptr, ce, G0, N);
  gemm_node<128, 16, true, false><<<gb, 128, 0, stream>>>(G0, ea2_w2, (float*)d_out, ea2_b2, degi, nullptr, N, 0);
}

// Round 7
// 497.711 us; speedup vs baseline: 1.9044x; 1.0818x over previous
//
#include <hip/hip_runtime.h>

typedef unsigned short u16;
typedef unsigned int u32;

using bfrag  = __attribute__((ext_vector_type(8))) short;   // 8 bf16 (4 VGPRs)
using f32x4  = __attribute__((ext_vector_type(4))) float;   // 4 fp32 acc
using f32x16 = __attribute__((ext_vector_type(16))) float;  // 16 fp32 acc (32x32 MFMA)

// ---------- bf16 / f16 helpers ----------
__device__ __forceinline__ float b2f(u16 u) {
  union { u32 i; float f; } c; c.i = ((u32)u) << 16; return c.f;
}
__device__ __forceinline__ float bflo(u32 u) { union { u32 i; float f; } c; c.i = u << 16; return c.f; }
__device__ __forceinline__ float bfhi(u32 u) { union { u32 i; float f; } c; c.i = u & 0xffff0000u; return c.f; }
__device__ __forceinline__ u16 f2b(float f) {  // round-to-nearest-even
  union { float f; u32 i; } c; c.f = f;
  u32 x = c.i;
  u32 r = x + 0x7fffu + ((x >> 16) & 1u);
  return (u16)(r >> 16);
}
__device__ __forceinline__ u32 packb2(float x, float y) {
  return ((u32)f2b(x)) | (((u32)f2b(y)) << 16);
}
__device__ __forceinline__ u16 f2h(float x) {
  union { _Float16 h; u16 u; } c; c.h = (_Float16)x; return c.u;
}
__device__ __forceinline__ float h2lo(u32 u) { union { u32 i; _Float16 h[2]; } c; c.i = u; return (float)c.h[0]; }
__device__ __forceinline__ float h2hi(u32 u) { union { u32 i; _Float16 h[2]; } c; c.i = u; return (float)c.h[1]; }
__device__ __forceinline__ int rfl(int v) { return __builtin_amdgcn_readfirstlane(v); }

// ---------- CSR build ----------
__global__ __launch_bounds__(256) void count_deg(const int* __restrict__ eidx,
                                                 int* __restrict__ degi, int E) {
  int e = blockIdx.x * 256 + threadIdx.x;
  if (e >= E) return;
  atomicAdd(&degi[eidx[E + e]], 1);
  atomicAdd(&degi[eidx[e]], 1);
}

__global__ __launch_bounds__(1024) void csr_scan(const int* __restrict__ degi,
                                                 int* __restrict__ rowptr,
                                                 float* __restrict__ dis, int n) {
  __shared__ int sums[1024];
  int tid = threadIdx.x;
  const int CH = (n + 1023) / 1024;
  int base = tid * CH;
  int s = 0;
  for (int i = 0; i < CH; ++i) { int j = base + i; if (j < n) s += degi[j]; }
  sums[tid] = s;
  __syncthreads();
  for (int off = 1; off < 1024; off <<= 1) {
    int v = sums[tid];
    int add = (tid >= off) ? sums[tid - off] : 0;
    __syncthreads();
    sums[tid] = v + add;
    __syncthreads();
  }
  int run = sums[tid] - s;
  for (int i = 0; i < CH; ++i) {
    int j = base + i;
    if (j < n) { rowptr[j] = run; run += degi[j]; }
  }
  if (tid == 1023) rowptr[n] = sums[1023];
  for (int j = tid; j < n; j += 1024) {
    int d = degi[j];
    dis[j] = d > 0 ? rsqrtf((float)d) : 0.0f;
  }
}

// cw[pos] = (src, bits(dis[src])); ce[pos] = (src, edge_id)
__global__ __launch_bounds__(256) void fill_csr(const int* __restrict__ eidx,
                                                const int* __restrict__ rowptr,
                                                int* __restrict__ cursor,
                                                const float* __restrict__ dis,
                                                int2* __restrict__ cw,
                                                int2* __restrict__ ce, int E) {
  int i = blockIdx.x * 256 + threadIdx.x;
  int E2 = 2 * E;
  if (i >= E2) return;
  int e = (i < E) ? i : i - E;
  int s, d;
  if (i < E) { s = eidx[e]; d = eidx[E + e]; }
  else       { s = eidx[E + e]; d = eidx[e]; }
  int pos = rowptr[d] + atomicAdd(&cursor[d], 1);
  cw[pos] = make_int2(s, __float_as_int(dis[s]));
  ce[pos] = make_int2(s, e);
}

// ---------- weight prep: fp32 [128k][128n] -> bf16 [128n][128k] ----------
__global__ __launch_bounds__(256) void prep_wt(
    const float* __restrict__ ea0_w2, const float* __restrict__ tag0_w,
    const float* __restrict__ ea1_w1, const float* __restrict__ ea1_w2,
    const float* __restrict__ tag1_w, const float* __restrict__ ea2_w1,
    u16* __restrict__ Wt) {
  int mat = blockIdx.x >> 3, chunk = blockIdx.x & 7;
  const float* src;
  if      (mat == 0)  src = ea0_w2;
  else if (mat <= 4)  src = tag0_w + (mat - 1) * 16384;
  else if (mat == 5)  src = ea1_w1;
  else if (mat == 6)  src = ea1_w1 + 16384;
  else if (mat == 7)  src = ea1_w2;
  else if (mat <= 11) src = tag1_w + (mat - 8) * 16384;
  else if (mat == 12) src = ea2_w1;
  else                src = ea2_w1 + 16384;
  u16* dst = Wt + mat * 16384;
  int t = threadIdx.x;
  for (int i = 0; i < 8; ++i) {
    int idx = chunk * 2048 + i * 256 + t;
    int k = idx >> 7, n = idx & 127;
    dst[n * 128 + k] = f2b(src[idx]);
  }
}

// ---------- prep 3 edge-proj weights: fp32 [16][128] -> bf16 [128n][16k] ----------
__global__ __launch_bounds__(256) void prep_wt_ea(
    const float* __restrict__ wA, const float* __restrict__ wB,
    const float* __restrict__ wC, u16* __restrict__ W3) {
  int tab = blockIdx.x;
  const float* src = (tab == 0) ? wA : (tab == 1) ? wB : wC;
  u16* dst = W3 + tab * 2048;
  int t = threadIdx.x;
  for (int i = 0; i < 8; ++i) {
    int idx = i * 256 + t;
    int n = idx >> 4, k = idx & 15;
    dst[idx] = f2b(src[k * 128 + n]);
  }
}

// ---------- edge projection via MFMA 32x32x16: P_l[e,:] = ea[e,:16] @ W_l  (f16) ----------
__global__ __launch_bounds__(256) void ea_proj_mfma(
    const float* __restrict__ ea, const u16* __restrict__ W3,
    u16* __restrict__ P0, u16* __restrict__ P1, u16* __restrict__ P2, int E) {
  __shared__ u16 Alds[64 * 16];     // 2 KB
  __shared__ u16 Wlds[3 * 2048];    // 12 KB
  int t = threadIdx.x;
  int base = blockIdx.x * 64;
  int rows = E - base; if (rows > 64) rows = 64;
#pragma unroll
  for (int i = 0; i < 3; ++i)
    *(uint4*)(Wlds + (i * 256 + t) * 8) = *(const uint4*)(W3 + (i * 256 + t) * 8);
#pragma unroll
  for (int i = 0; i < 4; ++i) {
    int idx = (i * 256 + t) * 4;                 // float index within tile (0..4095)
    float4 v = make_float4(0.f, 0.f, 0.f, 0.f);
    if ((idx >> 4) < rows) v = *(const float4*)(ea + (size_t)base * 16 + idx);
    ushort4 h;
    h.x = f2b(v.x); h.y = f2b(v.y); h.z = f2b(v.z); h.w = f2b(v.w);
    *(ushort4*)(Alds + idx) = h;
  }
  __syncthreads();
  int wave = t >> 6, lane = t & 63;
  int rowt = (wave >> 1) * 32;      // 0 / 32
  int colt = (wave & 1) * 64;       // 0 / 64
  int mm = lane & 31, kh = lane >> 5;
  bfrag a = *(const bfrag*)(Alds + (rowt + mm) * 16 + kh * 8);
#pragma unroll
  for (int tab = 0; tab < 3; ++tab) {
    const u16* wl = Wlds + tab * 2048;
    bfrag b0 = *(const bfrag*)(wl + (colt + mm) * 16 + kh * 8);
    bfrag b1 = *(const bfrag*)(wl + (colt + 32 + mm) * 16 + kh * 8);
    f32x16 acc0 = {0.f}, acc1 = {0.f};
#pragma unroll
    for (int z = 0; z < 16; ++z) { acc0[z] = 0.f; acc1[z] = 0.f; }
    acc0 = __builtin_amdgcn_mfma_f32_32x32x16_bf16(a, b0, acc0, 0, 0, 0);
    acc1 = __builtin_amdgcn_mfma_f32_32x32x16_bf16(a, b1, acc1, 0, 0, 0);
    u16* P = (tab == 0) ? P0 : (tab == 1) ? P1 : P2;
#pragma unroll
    for (int reg = 0; reg < 16; ++reg) {
      int row = rowt + (reg & 3) + 8 * (reg >> 2) + 4 * kh;
      if (row < rows) {
        size_t off = (size_t)(base + row) * 128;
        P[off + colt + mm]      = f2h(acc0[reg]);
        P[off + colt + 32 + mm] = f2h(acc1[reg]);
      }
    }
  }
}

// ---------- MFMA GEMM: C[M,128] = A[M,128]bf16 @ W (+bias/deg*bias +relu) ----------
template<bool OUTBF16>
__global__ __launch_bounds__(256) void gemm_mfma(
    const u16* __restrict__ A, const u16* __restrict__ Wt,
    void* __restrict__ Cout, const float* __restrict__ bias,
    const int* __restrict__ degi, int M, int relu) {
  __shared__ u16 Alds[64 * 136];
  __shared__ u16 Wlds[128 * 136];
  int t = threadIdx.x;
  int base = blockIdx.x * 64;
#pragma unroll
  for (int i = 0; i < 8; ++i) {
    int idx = (i * 256 + t) * 8;
    int n = idx >> 7, k = idx & 127;
    uint4 v = *(const uint4*)(Wt + idx);
    *(uint4*)(Wlds + n * 136 + k) = v;
  }
#pragma unroll
  for (int i = 0; i < 4; ++i) {
    int idx = (i * 256 + t) * 8;
    int r = idx >> 7, k = idx & 127;
    int row = base + r;
    uint4 v = make_uint4(0, 0, 0, 0);
    if (row < M) v = *(const uint4*)(A + (size_t)row * 128 + k);
    *(uint4*)(Alds + r * 136 + k) = v;
  }
  __syncthreads();
  int wave = t >> 6, lane = t & 63;
  int m = lane & 15, quad = lane >> 4;
  int arow = wave * 16 + m;
  bfrag a[4];
#pragma unroll
  for (int ks = 0; ks < 4; ++ks)
    a[ks] = *(const bfrag*)(Alds + arow * 136 + ks * 32 + quad * 8);
  f32x4 acc[8];
#pragma unroll
  for (int nt = 0; nt < 8; ++nt) acc[nt] = (f32x4){0.f, 0.f, 0.f, 0.f};
#pragma unroll
  for (int nt = 0; nt < 8; ++nt) {
    int n = nt * 16 + m;
#pragma unroll
    for (int ks = 0; ks < 4; ++ks) {
      bfrag b = *(const bfrag*)(Wlds + n * 136 + ks * 32 + quad * 8);
      acc[nt] = __builtin_amdgcn_mfma_f32_16x16x32_bf16(a[ks], b, acc[nt], 0, 0, 0);
    }
  }
#pragma unroll
  for (int nt = 0; nt < 8; ++nt) {
    int col = nt * 16 + m;
#pragma unroll
    for (int r = 0; r < 4; ++r) {
      int row = base + wave * 16 + quad * 4 + r;
      if (row < M) {
        float v = acc[nt][r];
        if (bias) { float b = bias[col]; v += degi ? b * (float)degi[row] : b; }
        if (relu) v = fmaxf(v, 0.f);
        if (OUTBF16) ((u16*)Cout)[(size_t)row * 128 + col] = f2b(v);
        else         ((float*)Cout)[(size_t)row * 128 + col] = v;
      }
    }
  }
}

// ---------- dual MFMA GEMM: C0 = A@W0 (+bias0), C1 = A@W1 (both bf16) ----------
__global__ __launch_bounds__(256) void gemm_mfma_dual(
    const u16* __restrict__ A, const u16* __restrict__ W0t, const u16* __restrict__ W1t,
    u16* __restrict__ C0, u16* __restrict__ C1, const float* __restrict__ bias0, int M) {
  __shared__ u16 Alds[64 * 136];
  __shared__ u16 Wlds[128 * 136];
  int t = threadIdx.x;
  int base = blockIdx.x * 64;
#pragma unroll
  for (int i = 0; i < 8; ++i) {
    int idx = (i * 256 + t) * 8;
    int n = idx >> 7, k = idx & 127;
    uint4 v = *(const uint4*)(W0t + idx);
    *(uint4*)(Wlds + n * 136 + k) = v;
  }
#pragma unroll
  for (int i = 0; i < 4; ++i) {
    int idx = (i * 256 + t) * 8;
    int r = idx >> 7, k = idx & 127;
    int row = base + r;
    uint4 v = make_uint4(0, 0, 0, 0);
    if (row < M) v = *(const uint4*)(A + (size_t)row * 128 + k);
    *(uint4*)(Alds + r * 136 + k) = v;
  }
  __syncthreads();
  int wave = t >> 6, lane = t & 63;
  int m = lane & 15, quad = lane >> 4;
  int arow = wave * 16 + m;
  bfrag a[4];
#pragma unroll
  for (int ks = 0; ks < 4; ++ks)
    a[ks] = *(const bfrag*)(Alds + arow * 136 + ks * 32 + quad * 8);
  f32x4 acc0[8], acc1[8];
#pragma unroll
  for (int nt = 0; nt < 8; ++nt) { acc0[nt] = (f32x4){0,0,0,0}; acc1[nt] = (f32x4){0,0,0,0}; }
#pragma unroll
  for (int nt = 0; nt < 8; ++nt) {
    int n = nt * 16 + m;
#pragma unroll
    for (int ks = 0; ks < 4; ++ks) {
      bfrag b = *(const bfrag*)(Wlds + n * 136 + ks * 32 + quad * 8);
      acc0[nt] = __builtin_amdgcn_mfma_f32_16x16x32_bf16(a[ks], b, acc0[nt], 0, 0, 0);
    }
  }
  __syncthreads();
#pragma unroll
  for (int i = 0; i < 8; ++i) {
    int idx = (i * 256 + t) * 8;
    int n = idx >> 7, k = idx & 127;
    uint4 v = *(const uint4*)(W1t + idx);
    *(uint4*)(Wlds + n * 136 + k) = v;
  }
  __syncthreads();
#pragma unroll
  for (int nt = 0; nt < 8; ++nt) {
    int n = nt * 16 + m;
#pragma unroll
    for (int ks = 0; ks < 4; ++ks) {
      bfrag b = *(const bfrag*)(Wlds + n * 136 + ks * 32 + quad * 8);
      acc1[nt] = __builtin_amdgcn_mfma_f32_16x16x32_bf16(a[ks], b, acc1[nt], 0, 0, 0);
    }
  }
#pragma unroll
  for (int nt = 0; nt < 8; ++nt) {
    int col = nt * 16 + m;
#pragma unroll
    for (int r = 0; r < 4; ++r) {
      int row = base + wave * 16 + quad * 4 + r;
      if (row < M) {
        float v0 = acc0[nt][r];
        if (bias0) v0 += bias0[col];
        C0[(size_t)row * 128 + col] = f2b(v0);
        C1[(size_t)row * 128 + col] = f2b(acc1[nt][r]);
      }
    }
  }
}

// ---------- VALU GEMM (small K or small KO) ----------
template<int KI, int KO, bool ABF16, bool OUTBF16>
__global__ __launch_bounds__(128) void gemm_node(
    const void* __restrict__ A_, const float* __restrict__ W, void* __restrict__ Cout,
    const float* __restrict__ bias, const int* __restrict__ degi,
    const float* __restrict__ resid, int M, int relu) {
  const int ROWS = 8;
  int t = threadIdx.x;
  int base = blockIdx.x * ROWS;
  __shared__ float Al[ROWS * KI];
  for (int i = t; i < ROWS * KI; i += 128) {
    int r = i / KI, k = i - r * KI;
    int row = base + r;
    float v = 0.f;
    if (row < M) {
      if (ABF16) v = b2f(((const u16*)A_)[(size_t)row * KI + k]);
      else       v = ((const float*)A_)[(size_t)row * KI + k];
    }
    Al[i] = v;
  }
  __syncthreads();
  if (KO == 128) {
    float acc[ROWS];
#pragma unroll
    for (int r = 0; r < ROWS; ++r) acc[r] = 0.f;
    for (int k = 0; k < KI; ++k) {
      float w = W[k * 128 + t];
#pragma unroll
      for (int r = 0; r < ROWS; ++r) acc[r] += Al[r * KI + k] * w;
    }
#pragma unroll
    for (int r = 0; r < ROWS; ++r) {
      int row = base + r;
      if (row >= M) break;
      float v = acc[r];
      if (bias)  { float b = bias[t]; v += degi ? b * (float)degi[row] : b; }
      if (resid) v += resid[(size_t)row * 128 + t];
      if (relu)  v = fmaxf(v, 0.f);
      if (OUTBF16) ((u16*)Cout)[(size_t)row * 128 + t] = f2b(v);
      else         ((float*)Cout)[(size_t)row * 128 + t] = v;
    }
  } else {
    int r = t >> 4, u = t & 15;
    int row = base + r;
    float acc = 0.f;
    for (int k = 0; k < KI; ++k) acc += Al[r * KI + k] * W[k * 16 + u];
    if (row < M) {
      float v = acc;
      if (bias)  { float b = bias[u]; v += degi ? b * (float)degi[row] : b; }
      if (resid) v += resid[(size_t)row * 16 + u];
      if (relu)  v = fmaxf(v, 0.f);
      if (OUTBF16) ((u16*)Cout)[(size_t)row * 16 + u] = f2b(v);
      else         ((float*)Cout)[(size_t)row * 16 + u] = v;
    }
  }
}

// ---------- TAG gather v4: scalar records, saddr row loads, fused Cin (+bias+relu) ----------
template<bool FINAL>
__global__ __launch_bounds__(256) void tag_gather4(
    const u16* __restrict__ g, const u16* __restrict__ Cin,
    const float* __restrict__ bias, const float* __restrict__ dis,
    const int* __restrict__ rowptr, const int2* __restrict__ cw,
    u16* __restrict__ out, int N) {
  int wave = threadIdx.x >> 6, lane = threadIdx.x & 63;
  int node = blockIdx.x * 4 + wave;
  if (node >= N) return;
  int e0 = rfl(rowptr[node]);
  int e1 = rfl(rowptr[node + 1]);
  float a0 = 0, a1 = 0, b0 = 0, b1 = 0;
  int e = e0;
  for (; e + 4 <= e1; e += 4) {
    int4 r01 = *(const int4*)(cw + e);
    int4 r23 = *(const int4*)(cw + e + 2);
    int s0 = rfl(r01.x); float w0 = __uint_as_float(rfl(r01.y));
    int s1 = rfl(r01.z); float w1 = __uint_as_float(rfl(r01.w));
    int s2 = rfl(r23.x); float w2 = __uint_as_float(rfl(r23.y));
    int s3 = rfl(r23.z); float w3 = __uint_as_float(rfl(r23.w));
    u32 h0 = *((const u32*)(g + (size_t)s0 * 128) + lane);
    u32 h1 = *((const u32*)(g + (size_t)s1 * 128) + lane);
    u32 h2 = *((const u32*)(g + (size_t)s2 * 128) + lane);
    u32 h3 = *((const u32*)(g + (size_t)s3 * 128) + lane);
    a0 += w0 * bflo(h0); a1 += w0 * bfhi(h0);
    b0 += w1 * bflo(h1); b1 += w1 * bfhi(h1);
    a0 += w2 * bflo(h2); a1 += w2 * bfhi(h2);
    b0 += w3 * bflo(h3); b1 += w3 * bfhi(h3);
  }
  for (; e < e1; ++e) {
    int2 r = cw[e];
    int s0 = rfl(r.x); float w0 = __uint_as_float(rfl(r.y));
    u32 h0 = *((const u32*)(g + (size_t)s0 * 128) + lane);
    a0 += w0 * bflo(h0); a1 += w0 * bfhi(h0);
  }
  float dn = dis[node];
  float r0v = dn * (a0 + b0), r1v = dn * (a1 + b1);
  u32 cin = *((const u32*)(Cin + (size_t)node * 128) + lane);
  r0v += bflo(cin); r1v += bfhi(cin);
  if (FINAL) {
    float2 bv = *(const float2*)(bias + 2 * lane);
    r0v = fmaxf(r0v + bv.x, 0.f);
    r1v = fmaxf(r1v + bv.y, 0.f);
  }
  *((u32*)(out + (size_t)node * 128) + lane) = packb2(r0v, r1v);
}

// ---------- EA gather v4: Hsum[n] = sum_e relu(pb[n] + q[src] + P[edge]) ----------
__global__ __launch_bounds__(256) void ea_gather4(
    const u16* __restrict__ pb, const u16* __restrict__ q,
    const u16* __restrict__ P /*f16 [E,128]*/,
    const int* __restrict__ rowptr, const int2* __restrict__ ce,
    u16* __restrict__ Hsum, int N) {
  int wave = threadIdx.x >> 6, lane = threadIdx.x & 63;
  int node = blockIdx.x * 4 + wave;
  if (node >= N) return;
  int e0 = rfl(rowptr[node]);
  int e1 = rfl(rowptr[node + 1]);
  u32 pbu = *((const u32*)(pb + (size_t)node * 128) + lane);
  float pb0 = bflo(pbu), pb1 = bfhi(pbu);
  float acc0 = 0, acc1 = 0;
  int e = e0;
  for (; e + 2 <= e1; e += 2) {
    int4 r01 = *(const int4*)(ce + e);
    int s0 = rfl(r01.x), p0i = rfl(r01.y);
    int s1 = rfl(r01.z), p1i = rfl(r01.w);
    u32 q0 = *((const u32*)(q + (size_t)s0 * 128) + lane);
    u32 v0 = *((const u32*)(P + (size_t)p0i * 128) + lane);
    u32 q1 = *((const u32*)(q + (size_t)s1 * 128) + lane);
    u32 v1 = *((const u32*)(P + (size_t)p1i * 128) + lane);
    float m0 = pb0 + bflo(q0) + h2lo(v0);
    float m1 = pb1 + bfhi(q0) + h2hi(v0);
    float n0 = pb0 + bflo(q1) + h2lo(v1);
    float n1 = pb1 + bfhi(q1) + h2hi(v1);
    acc0 += fmaxf(m0, 0.f) + fmaxf(n0, 0.f);
    acc1 += fmaxf(m1, 0.f) + fmaxf(n1, 0.f);
  }
  if (e < e1) {
    int2 r = ce[e];
    int s0 = rfl(r.x), p0i = rfl(r.y);
    u32 q0 = *((const u32*)(q + (size_t)s0 * 128) + lane);
    u32 v0 = *((const u32*)(P + (size_t)p0i * 128) + lane);
    acc0 += fmaxf(pb0 + bflo(q0) + h2lo(v0), 0.f);
    acc1 += fmaxf(pb1 + bfhi(q0) + h2hi(v0), 0.f);
  }
  *((u32*)(Hsum + (size_t)node * 128) + lane) = packb2(acc0, acc1);
}

extern "C" void kernel_launch(void* const* d_in, const int* in_sizes, int n_in,
                              void* d_out, int out_size, void* d_ws, size_t ws_size,
                              hipStream_t stream) {
  const float* x      = (const float*)d_in[0];
  const float* mask   = (const float*)d_in[1];
  const float* ea     = (const float*)d_in[2];
  const int*   eidx   = (const int*)d_in[3];
  const float* m_w1   = (const float*)d_in[4];
  const float* m_b1   = (const float*)d_in[5];
  const float* m_w2   = (const float*)d_in[6];
  const float* m_b2   = (const float*)d_in[7];
  const float* ea0_w1 = (const float*)d_in[8];
  const float* ea0_b1 = (const float*)d_in[9];
  const float* ea0_w2 = (const float*)d_in[10];
  const float* ea0_b2 = (const float*)d_in[11];
  const float* tag0_w = (const float*)d_in[12];
  const float* tag0_b = (const float*)d_in[13];
  const float* ea1_w1 = (const float*)d_in[14];
  const float* ea1_b1 = (const float*)d_in[15];
  const float* ea1_w2 = (const float*)d_in[16];
  const float* ea1_b2 = (const float*)d_in[17];
  const float* tag1_w = (const float*)d_in[18];
  const float* tag1_b = (const float*)d_in[19];
  const float* ea2_w1 = (const float*)d_in[20];
  const float* ea2_b1 = (const float*)d_in[21];
  const float* ea2_w2 = (const float*)d_in[22];
  const float* ea2_b2 = (const float*)d_in[23];

  const int N = in_sizes[0] / 16;   // 20000
  const int E = in_sizes[2] / 16;   // 160000
  const int E2 = 2 * E;

  char* w = (char*)d_ws;
  auto alloc = [&](size_t bytes) { char* p = w; w += (bytes + 255) & ~(size_t)255; return p; };
  int*   degi   = (int*)alloc((size_t)N * 4);
  int*   cursor = (int*)alloc((size_t)N * 4);
  int*   rowptr = (int*)alloc((size_t)(N + 1) * 4);
  float* dis    = (float*)alloc((size_t)N * 4);
  int2*  cw     = (int2*)alloc((size_t)E2 * 8);
  int2*  ce     = (int2*)alloc((size_t)E2 * 8);
  float* Hf     = (float*)alloc((size_t)N * 128 * 4);
  float* h16    = (float*)alloc((size_t)N * 16 * 4);
  u16*   X0     = (u16*)alloc((size_t)N * 128 * 2);
  u16*   X1     = (u16*)alloc((size_t)N * 128 * 2);
  u16*   X2     = (u16*)alloc((size_t)N * 128 * 2);
  u16*   G0     = (u16*)alloc((size_t)N * 128 * 2);
  u16*   G1     = (u16*)alloc((size_t)N * 128 * 2);
  u16*   G2     = (u16*)alloc((size_t)N * 128 * 2);
  u16*   G3     = (u16*)alloc((size_t)N * 128 * 2);
  u16*   Wt     = (u16*)alloc((size_t)14 * 16384 * 2);
  u16*   W3     = (u16*)alloc((size_t)3 * 2048 * 2);
  u16*   P0     = (u16*)alloc((size_t)E * 128 * 2);   // f16 tables
  u16*   P1     = (u16*)alloc((size_t)E * 128 * 2);
  u16*   P2     = (u16*)alloc((size_t)E * 128 * 2);
  (void)ws_size; (void)n_in; (void)out_size;

  hipMemsetAsync(degi, 0, (size_t)N * 4, stream);
  hipMemsetAsync(cursor, 0, (size_t)N * 4, stream);
  prep_wt<<<112, 256, 0, stream>>>(ea0_w2, tag0_w, ea1_w1, ea1_w2, tag1_w, ea2_w1, Wt);
  prep_wt_ea<<<3, 256, 0, stream>>>(ea0_w1 + 32 * 128, ea1_w1 + 256 * 128,
                                    ea2_w1 + 256 * 128, W3);
  ea_proj_mfma<<<(E + 63) / 64, 256, 0, stream>>>(ea, W3, P0, P1, P2, E);
  count_deg<<<(E + 255) / 256, 256, 0, stream>>>(eidx, degi, E);
  csr_scan<<<1, 1024, 0, stream>>>(degi, rowptr, dis, N);
  fill_csr<<<(E2 + 255) / 256, 256, 0, stream>>>(eidx, rowptr, cursor, dis, cw, ce, E);

  const int gb = (N + 7) / 8;
  const int gm = (N + 63) / 64;
  const int g4 = (N + 3) / 4;
  u16* WT_ea0w2  = Wt + 0 * 16384;
  u16* WT_tag0   = Wt + 1 * 16384;
  u16* WT_ea1d   = Wt + 5 * 16384;
  u16* WT_ea1s   = Wt + 6 * 16384;
  u16* WT_ea1w2  = Wt + 7 * 16384;
  u16* WT_tag1   = Wt + 8 * 16384;
  u16* WT_ea2d   = Wt + 12 * 16384;
  u16* WT_ea2s   = Wt + 13 * 16384;

  // ---- mask MLP + residual: h16 = relu(mask@m_w1+b1)@m_w2 + b2 + x ----
  gemm_node<16, 128, false, false><<<gb, 128, 0, stream>>>(mask, m_w1, Hf, m_b1, nullptr, nullptr, N, 1);
  gemm_node<128, 16, false, false><<<gb, 128, 0, stream>>>(Hf, m_w2, h16, m_b2, nullptr, x, N, 0);

  // ---- EA0 ----
  gemm_node<16, 128, false, true><<<gb, 128, 0, stream>>>(h16, ea0_w1, X0, ea0_b1, nullptr, nullptr, N, 0);
  gemm_node<16, 128, false, true><<<gb, 128, 0, stream>>>(h16, ea0_w1 + 16 * 128, X1, nullptr, nullptr, nullptr, N, 0);
  ea_gather4<<<g4, 256, 0, stream>>>(X0, X1, P0, rowptr, ce, X2, N);
  gemm_mfma<true><<<gm, 256, 0, stream>>>(X2, WT_ea0w2, X0, ea0_b2, degi, N, 1);   // h1 -> X0

  // ---- TAG0: g_k = h1@lin_k; h2 = relu(g0 + L(g1 + L(g2 + L g3)) + b) ----
  gemm_mfma_dual<<<gm, 256, 0, stream>>>(X0, WT_tag0, WT_tag0 + 16384, G0, G1, nullptr, N);
  gemm_mfma_dual<<<gm, 256, 0, stream>>>(X0, WT_tag0 + 2 * 16384, WT_tag0 + 3 * 16384, G2, G3, nullptr, N);
  tag_gather4<false><<<g4, 256, 0, stream>>>(G3, G2, nullptr, dis, rowptr, cw, X1, N);
  tag_gather4<false><<<g4, 256, 0, stream>>>(X1, G1, nullptr, dis, rowptr, cw, X2, N);
  tag_gather4<true><<<g4, 256, 0, stream>>>(X2, G0, tag0_b, dis, rowptr, cw, X0, N);  // h2 -> X0

  // ---- EA1 ----
  gemm_mfma_dual<<<gm, 256, 0, stream>>>(X0, WT_ea1d, WT_ea1s, X1, X2, ea1_b1, N);
  ea_gather4<<<g4, 256, 0, stream>>>(X1, X2, P1, rowptr, ce, G0, N);
  gemm_mfma<true><<<gm, 256, 0, stream>>>(G0, WT_ea1w2, X0, ea1_b2, degi, N, 1);   // h3 -> X0

  // ---- TAG1 ----
  gemm_mfma_dual<<<gm, 256, 0, stream>>>(X0, WT_tag1, WT_tag1 + 16384, G0, G1, nullptr, N);
  gemm_mfma_dual<<<gm, 256, 0, stream>>>(X0, WT_tag1 + 2 * 16384, WT_tag1 + 3 * 16384, G2, G3, nullptr, N);
  tag_gather4<false><<<g4, 256, 0, stream>>>(G3, G2, nullptr, dis, rowptr, cw, X1, N);
  tag_gather4<false><<<g4, 256, 0, stream>>>(X1, G1, nullptr, dis, rowptr, cw, X2, N);
  tag_gather4<true><<<g4, 256, 0, stream>>>(X2, G0, tag1_b, dis, rowptr, cw, X0, N);  // h4 -> X0

  // ---- EA2 (final, out 16, fp32) ----
  gemm_mfma_dual<<<gm, 256, 0, stream>>>(X0, WT_ea2d, WT_ea2s, X1, X2, ea2_b1, N);
  ea_gather4<<<g4, 256, 0, stream>>>(X1, X2, P2, rowptr, ce, G0, N);
  gemm_node<128, 16, true, false><<<gb, 128, 0, stream>>>(G0, ea2_w2, (float*)d_out, ea2_b2, degi, nullptr, N, 0);
}